// Round 3
// baseline (577.485 us; speedup 1.0000x reference)
//
#include <hip/hip_runtime.h>
#include <hip/hip_bf16.h>
#include <math.h>

typedef __bf16 bf16_t;
typedef __bf16 bf16x8 __attribute__((ext_vector_type(8)));
typedef __bf16 bf16x4 __attribute__((ext_vector_type(4)));
typedef float  f32x4  __attribute__((ext_vector_type(4)));

#define L_DIM 2048
#define D_DIM 1024
#define H_DIM 16
#define M_DIM 4096
#define KTOP 409
#define SLOTS 416   // 26 * 16

// split f32 into bf16 hi + bf16 lo (a ~= hi + lo, |a-hi-lo| <= 2^-18 |a|)
__device__ __forceinline__ void split2(float a, bf16_t& h, bf16_t& l) {
  h = (bf16_t)a;
  l = (bf16_t)(a - (float)h);
}

// ---------------------------------------------------------------------------
// QKV GEMM, f32 in, split-bf16 3-product MFMA, f32 accumulate.
// C[m,n] = sum_k A[m,k] * W[n,k] + bias[n].  A:[4096,1024] f32, W:[1024,1024] f32.
// z=0 -> Q (hi/lo) + fp32 per-head row norms; z=1 -> K (hi/lo);
// z=2 -> V transposed: VT[(b*1024+col)*2048 + l] (hi/lo).
// ---------------------------------------------------------------------------
__global__ __launch_bounds__(256) void gemm_qkv(
    const float* __restrict__ A,
    const float* __restrict__ W0, const float* __restrict__ W1, const float* __restrict__ W2,
    const float* __restrict__ b0, const float* __restrict__ b1, const float* __restrict__ b2,
    bf16_t* __restrict__ Qhi, bf16_t* __restrict__ Qlo,
    bf16_t* __restrict__ Khi, bf16_t* __restrict__ Klo,
    bf16_t* __restrict__ Vhi, bf16_t* __restrict__ Vlo,
    float* __restrict__ norms)
{
  const int z = blockIdx.z;
  const float* W    = (z == 0) ? W0 : (z == 1) ? W1 : W2;
  const float* bias = (z == 0) ? b0 : (z == 1) ? b1 : b2;
  bf16_t* Chi = (z == 0) ? Qhi : (z == 1) ? Khi : Vhi;
  bf16_t* Clo = (z == 0) ? Qlo : (z == 1) ? Klo : Vlo;
  const bool do_norm = (z == 0);
  const bool trans   = (z == 2);

  const int n0   = blockIdx.x * 128;
  const int row0 = blockIdx.y * 128;

  __shared__ __align__(16) bf16_t sAhi[128][40];
  __shared__ __align__(16) bf16_t sAlo[128][40];
  __shared__ __align__(16) bf16_t sBhi[128][40];
  __shared__ __align__(16) bf16_t sBlo[128][40];

  const int tid  = threadIdx.x;
  const int lane = tid & 63;
  const int wave = tid >> 6;
  const int wr = wave >> 1, wc = wave & 1;
  const int lm = lane & 15, quad = lane >> 4;

  const f32x4 vzero = {0.f, 0.f, 0.f, 0.f};
  f32x4 acc[4][4];
  #pragma unroll
  for (int mi = 0; mi < 4; ++mi)
    #pragma unroll
    for (int ni = 0; ni < 4; ++ni) acc[mi][ni] = vzero;

  for (int k0 = 0; k0 < D_DIM; k0 += 32) {
    __syncthreads();
    #pragma unroll
    for (int i = 0; i < 4; ++i) {
      int t  = tid + i * 256;     // 0..1023
      int rr = t >> 3;            // 0..127
      int cc = (t & 7) * 4;       // 0..28
      f32x4 av = *reinterpret_cast<const f32x4*>(&A[(size_t)(row0 + rr) * D_DIM + k0 + cc]);
      f32x4 wv = *reinterpret_cast<const f32x4*>(&W[(size_t)(n0  + rr) * D_DIM + k0 + cc]);
      bf16x4 ah, al, wh, wl;
      #pragma unroll
      for (int j = 0; j < 4; ++j) {
        bf16_t h, l;
        split2(av[j], h, l); ah[j] = h; al[j] = l;
        split2(wv[j], h, l); wh[j] = h; wl[j] = l;
      }
      *reinterpret_cast<bf16x4*>(&sAhi[rr][cc]) = ah;
      *reinterpret_cast<bf16x4*>(&sAlo[rr][cc]) = al;
      *reinterpret_cast<bf16x4*>(&sBhi[rr][cc]) = wh;
      *reinterpret_cast<bf16x4*>(&sBlo[rr][cc]) = wl;
    }
    __syncthreads();
    bf16x8 afh[4], afl[4], bfh[4], bfl[4];
    #pragma unroll
    for (int mi = 0; mi < 4; ++mi) {
      afh[mi] = *reinterpret_cast<const bf16x8*>(&sAhi[wr * 64 + mi * 16 + lm][quad * 8]);
      afl[mi] = *reinterpret_cast<const bf16x8*>(&sAlo[wr * 64 + mi * 16 + lm][quad * 8]);
    }
    #pragma unroll
    for (int ni = 0; ni < 4; ++ni) {
      bfh[ni] = *reinterpret_cast<const bf16x8*>(&sBhi[wc * 64 + ni * 16 + lm][quad * 8]);
      bfl[ni] = *reinterpret_cast<const bf16x8*>(&sBlo[wc * 64 + ni * 16 + lm][quad * 8]);
    }
    #pragma unroll
    for (int mi = 0; mi < 4; ++mi)
      #pragma unroll
      for (int ni = 0; ni < 4; ++ni) {
        acc[mi][ni] = __builtin_amdgcn_mfma_f32_16x16x32_bf16(afh[mi], bfh[ni], acc[mi][ni], 0, 0, 0);
        acc[mi][ni] = __builtin_amdgcn_mfma_f32_16x16x32_bf16(afh[mi], bfl[ni], acc[mi][ni], 0, 0, 0);
        acc[mi][ni] = __builtin_amdgcn_mfma_f32_16x16x32_bf16(afl[mi], bfh[ni], acc[mi][ni], 0, 0, 0);
      }
  }

  float bv[4];
  #pragma unroll
  for (int ni = 0; ni < 4; ++ni) bv[ni] = bias[n0 + wc * 64 + ni * 16 + lm];
  #pragma unroll
  for (int mi = 0; mi < 4; ++mi)
    #pragma unroll
    for (int ni = 0; ni < 4; ++ni)
      #pragma unroll
      for (int r = 0; r < 4; ++r) acc[mi][ni][r] += bv[ni];

  if (do_norm) {
    // one wave spans one head (64 cols); f32 norms from accumulators
    const int h = (n0 + wc * 64) >> 6;
    #pragma unroll
    for (int mi = 0; mi < 4; ++mi)
      #pragma unroll
      for (int r = 0; r < 4; ++r) {
        float s = 0.f;
        #pragma unroll
        for (int ni = 0; ni < 4; ++ni) { float v = acc[mi][ni][r]; s += v * v; }
        s += __shfl_xor(s, 1); s += __shfl_xor(s, 2);
        s += __shfl_xor(s, 4); s += __shfl_xor(s, 8);
        if (lm == 0) {
          int row = row0 + wr * 64 + mi * 16 + quad * 4 + r;
          int bb = row >> 11, ll = row & (L_DIM - 1);
          norms[(bb * H_DIM + h) * L_DIM + ll] = s;
        }
      }
  }

  if (!trans) {
    #pragma unroll
    for (int mi = 0; mi < 4; ++mi)
      #pragma unroll
      for (int r = 0; r < 4; ++r) {
        int row = row0 + wr * 64 + mi * 16 + quad * 4 + r;
        #pragma unroll
        for (int ni = 0; ni < 4; ++ni) {
          int col = n0 + wc * 64 + ni * 16 + lm;
          bf16_t h, l;
          split2(acc[mi][ni][r], h, l);
          Chi[(size_t)row * D_DIM + col] = h;
          Clo[(size_t)row * D_DIM + col] = l;
        }
      }
  } else {
    #pragma unroll
    for (int mi = 0; mi < 4; ++mi) {
      int rbase = row0 + wr * 64 + mi * 16 + quad * 4;
      int bb = rbase >> 11, l0 = rbase & (L_DIM - 1);
      #pragma unroll
      for (int ni = 0; ni < 4; ++ni) {
        int col = n0 + wc * 64 + ni * 16 + lm;
        bf16x4 wh, wl;
        #pragma unroll
        for (int r = 0; r < 4; ++r) {
          bf16_t h, l;
          split2(acc[mi][ni][r], h, l);
          wh[r] = h; wl[r] = l;
        }
        size_t o = ((size_t)(bb * D_DIM + col)) * L_DIM + l0;
        *reinterpret_cast<bf16x4*>(&Vhi[o]) = wh;
        *reinterpret_cast<bf16x4*>(&Vlo[o]) = wl;
      }
    }
  }
}

// ---------------------------------------------------------------------------
// Output projection: A = AO as bf16 hi/lo pair, W = Wo f32, C = f32 out.
// ---------------------------------------------------------------------------
__global__ __launch_bounds__(256) void gemm_out(
    const bf16_t* __restrict__ Ahi, const bf16_t* __restrict__ Alo,
    const float* __restrict__ W, const float* __restrict__ bias,
    float* __restrict__ C)
{
  const int n0   = blockIdx.x * 128;
  const int row0 = blockIdx.y * 128;

  __shared__ __align__(16) bf16_t sAhi[128][40];
  __shared__ __align__(16) bf16_t sAlo[128][40];
  __shared__ __align__(16) bf16_t sBhi[128][40];
  __shared__ __align__(16) bf16_t sBlo[128][40];

  const int tid  = threadIdx.x;
  const int lane = tid & 63;
  const int wave = tid >> 6;
  const int wr = wave >> 1, wc = wave & 1;
  const int lm = lane & 15, quad = lane >> 4;

  const f32x4 vzero = {0.f, 0.f, 0.f, 0.f};
  f32x4 acc[4][4];
  #pragma unroll
  for (int mi = 0; mi < 4; ++mi)
    #pragma unroll
    for (int ni = 0; ni < 4; ++ni) acc[mi][ni] = vzero;

  for (int k0 = 0; k0 < D_DIM; k0 += 32) {
    __syncthreads();
    #pragma unroll
    for (int i = 0; i < 2; ++i) {
      int t  = tid + i * 256;
      int rr = t >> 2;
      int cc = (t & 3) * 8;
      size_t idx = (size_t)(row0 + rr) * D_DIM + k0 + cc;
      *reinterpret_cast<bf16x8*>(&sAhi[rr][cc]) = *reinterpret_cast<const bf16x8*>(&Ahi[idx]);
      *reinterpret_cast<bf16x8*>(&sAlo[rr][cc]) = *reinterpret_cast<const bf16x8*>(&Alo[idx]);
    }
    #pragma unroll
    for (int i = 0; i < 4; ++i) {
      int t  = tid + i * 256;
      int rr = t >> 3;
      int cc = (t & 7) * 4;
      f32x4 wv = *reinterpret_cast<const f32x4*>(&W[(size_t)(n0 + rr) * D_DIM + k0 + cc]);
      bf16x4 wh, wl;
      #pragma unroll
      for (int j = 0; j < 4; ++j) { bf16_t h, l; split2(wv[j], h, l); wh[j] = h; wl[j] = l; }
      *reinterpret_cast<bf16x4*>(&sBhi[rr][cc]) = wh;
      *reinterpret_cast<bf16x4*>(&sBlo[rr][cc]) = wl;
    }
    __syncthreads();
    bf16x8 afh[4], afl[4], bfh[4], bfl[4];
    #pragma unroll
    for (int mi = 0; mi < 4; ++mi) {
      afh[mi] = *reinterpret_cast<const bf16x8*>(&sAhi[wr * 64 + mi * 16 + lm][quad * 8]);
      afl[mi] = *reinterpret_cast<const bf16x8*>(&sAlo[wr * 64 + mi * 16 + lm][quad * 8]);
    }
    #pragma unroll
    for (int ni = 0; ni < 4; ++ni) {
      bfh[ni] = *reinterpret_cast<const bf16x8*>(&sBhi[wc * 64 + ni * 16 + lm][quad * 8]);
      bfl[ni] = *reinterpret_cast<const bf16x8*>(&sBlo[wc * 64 + ni * 16 + lm][quad * 8]);
    }
    #pragma unroll
    for (int mi = 0; mi < 4; ++mi)
      #pragma unroll
      for (int ni = 0; ni < 4; ++ni) {
        acc[mi][ni] = __builtin_amdgcn_mfma_f32_16x16x32_bf16(afh[mi], bfh[ni], acc[mi][ni], 0, 0, 0);
        acc[mi][ni] = __builtin_amdgcn_mfma_f32_16x16x32_bf16(afh[mi], bfl[ni], acc[mi][ni], 0, 0, 0);
        acc[mi][ni] = __builtin_amdgcn_mfma_f32_16x16x32_bf16(afl[mi], bfh[ni], acc[mi][ni], 0, 0, 0);
      }
  }

  float bv[4];
  #pragma unroll
  for (int ni = 0; ni < 4; ++ni) bv[ni] = bias[n0 + wc * 64 + ni * 16 + lm];
  #pragma unroll
  for (int mi = 0; mi < 4; ++mi)
    #pragma unroll
    for (int r = 0; r < 4; ++r) {
      int row = row0 + wr * 64 + mi * 16 + quad * 4 + r;
      #pragma unroll
      for (int ni = 0; ni < 4; ++ni) {
        int col = n0 + wc * 64 + ni * 16 + lm;
        C[(size_t)row * D_DIM + col] = acc[mi][ni][r] + bv[ni];
      }
    }
}

// ---------------------------------------------------------------------------
// Exact top-409 per (b,h): bitonic sort (norm desc, idx asc) = lax.top_k order.
// ---------------------------------------------------------------------------
__global__ __launch_bounds__(256) void topk_kernel(
    const float* __restrict__ norms, int* __restrict__ sel)
{
  const int bh = blockIdx.x;
  __shared__ __align__(16) float val[L_DIM];
  __shared__ __align__(16) int   idx[L_DIM];
  const int t = threadIdx.x;
  for (int i = t; i < L_DIM; i += 256) {
    val[i] = norms[bh * L_DIM + i];
    idx[i] = i;
  }
  __syncthreads();
  for (int k = 2; k <= L_DIM; k <<= 1) {
    for (int j = k >> 1; j > 0; j >>= 1) {
      for (int i = t; i < L_DIM; i += 256) {
        int ixj = i ^ j;
        if (ixj > i) {
          float v1 = val[i], v2 = val[ixj];
          int   i1 = idx[i], i2 = idx[ixj];
          bool up = ((i & k) == 0);
          bool sw = up ? ((v2 > v1) || (v2 == v1 && i2 < i1))
                       : ((v1 > v2) || (v1 == v2 && i1 < i2));
          if (sw) { val[i] = v2; val[ixj] = v1; idx[i] = i2; idx[ixj] = i1; }
        }
      }
      __syncthreads();
    }
  }
  for (int i = t; i < SLOTS; i += 256)
    sel[bh * SLOTS + i] = (i < KTOP) ? idx[i] : -1;
}

// ---------------------------------------------------------------------------
// mean(V) to EVERY AO row (uniform softmax rows); attn overwrites selected.
// ---------------------------------------------------------------------------
__global__ __launch_bounds__(256) void meanfill_kernel(
    const bf16_t* __restrict__ VThi, const bf16_t* __restrict__ VTlo,
    bf16_t* __restrict__ AOhi, bf16_t* __restrict__ AOlo)
{
  const int bh = blockIdx.x;
  const int b = bh >> 4, h = bh & 15;
  const int t = threadIdx.x;
  __shared__ __align__(16) bf16_t smh[64];
  __shared__ __align__(16) bf16_t sml[64];
  {
    const int hd = t >> 2, part = t & 3;
    size_t base = ((size_t)(b * D_DIM + h * 64 + hd)) * L_DIM;
    float s = 0.f;
    for (int l0 = part * 512; l0 < part * 512 + 512; l0 += 8) {
      bf16x8 vh = *reinterpret_cast<const bf16x8*>(&VThi[base + l0]);
      bf16x8 vl = *reinterpret_cast<const bf16x8*>(&VTlo[base + l0]);
      #pragma unroll
      for (int j = 0; j < 8; ++j) s += (float)vh[j] + (float)vl[j];
    }
    s += __shfl_xor(s, 1);
    s += __shfl_xor(s, 2);
    if (part == 0) {
      bf16_t hh, ll;
      split2(s * (1.0f / (float)L_DIM), hh, ll);
      smh[hd] = hh; sml[hd] = ll;
    }
  }
  __syncthreads();
  const int lbase = blockIdx.y * 256;
  for (int i = t; i < 256 * 64; i += 256) {
    int l = lbase + (i >> 6), hd = i & 63;
    size_t o = ((size_t)(b * L_DIM + l)) * D_DIM + h * 64 + hd;
    AOhi[o] = smh[hd];
    AOlo[o] = sml[hd];
  }
}

// ---------------------------------------------------------------------------
// Flash attention over the 409 selected queries, split-bf16 3-product MFMA.
// One wave/block; 16 query slots/wave; 32-key tiles; P via LDS C->A transform.
// ---------------------------------------------------------------------------
__global__ __launch_bounds__(64) void attn_kernel(
    const bf16_t* __restrict__ Qhi, const bf16_t* __restrict__ Qlo,
    const bf16_t* __restrict__ Khi, const bf16_t* __restrict__ Klo,
    const bf16_t* __restrict__ VThi, const bf16_t* __restrict__ VTlo,
    const int* __restrict__ sel,
    bf16_t* __restrict__ AOhi, bf16_t* __restrict__ AOlo)
{
  const int bh = blockIdx.x / 26;
  const int qt = blockIdx.x % 26;
  const int b = bh >> 4, h = bh & 15;
  const int lane = threadIdx.x;
  const int lm = lane & 15, quad = lane >> 4;

  __shared__ __align__(16) bf16_t sPh[16][40];
  __shared__ __align__(16) bf16_t sPl[16][40];

  const int slot = qt * 16 + lm;
  const int qi = sel[bh * SLOTS + slot];
  const size_t qrow = (size_t)(b * L_DIM + (qi >= 0 ? qi : 0));
  const size_t qo = qrow * D_DIM + h * 64;
  const bf16x8 qa0h = *reinterpret_cast<const bf16x8*>(&Qhi[qo + quad * 8]);
  const bf16x8 qa0l = *reinterpret_cast<const bf16x8*>(&Qlo[qo + quad * 8]);
  const bf16x8 qa1h = *reinterpret_cast<const bf16x8*>(&Qhi[qo + 32 + quad * 8]);
  const bf16x8 qa1l = *reinterpret_cast<const bf16x8*>(&Qlo[qo + 32 + quad * 8]);

  const f32x4 vzero = {0.f, 0.f, 0.f, 0.f};
  float m_i[4], l_i[4];
  f32x4 o[4];
  #pragma unroll
  for (int r = 0; r < 4; ++r) { m_i[r] = -1.0e30f; l_i[r] = 0.f; }
  #pragma unroll
  for (int ni = 0; ni < 4; ++ni) o[ni] = vzero;

  const float scale = 0.125f;
  const size_t kbase = (size_t)(b * L_DIM) * D_DIM + h * 64;

  for (int kt = 0; kt < L_DIM; kt += 32) {
    f32x4 s0 = vzero, s1 = vzero;
    {
      size_t kr0 = kbase + (size_t)(kt + lm) * D_DIM;
      bf16x8 kb0h = *reinterpret_cast<const bf16x8*>(&Khi[kr0 + quad * 8]);
      bf16x8 kb0l = *reinterpret_cast<const bf16x8*>(&Klo[kr0 + quad * 8]);
      bf16x8 kb1h = *reinterpret_cast<const bf16x8*>(&Khi[kr0 + 32 + quad * 8]);
      bf16x8 kb1l = *reinterpret_cast<const bf16x8*>(&Klo[kr0 + 32 + quad * 8]);
      s0 = __builtin_amdgcn_mfma_f32_16x16x32_bf16(qa0h, kb0h, s0, 0, 0, 0);
      s0 = __builtin_amdgcn_mfma_f32_16x16x32_bf16(qa0h, kb0l, s0, 0, 0, 0);
      s0 = __builtin_amdgcn_mfma_f32_16x16x32_bf16(qa0l, kb0h, s0, 0, 0, 0);
      s0 = __builtin_amdgcn_mfma_f32_16x16x32_bf16(qa1h, kb1h, s0, 0, 0, 0);
      s0 = __builtin_amdgcn_mfma_f32_16x16x32_bf16(qa1h, kb1l, s0, 0, 0, 0);
      s0 = __builtin_amdgcn_mfma_f32_16x16x32_bf16(qa1l, kb1h, s0, 0, 0, 0);
      size_t kr1 = kbase + (size_t)(kt + 16 + lm) * D_DIM;
      bf16x8 kb2h = *reinterpret_cast<const bf16x8*>(&Khi[kr1 + quad * 8]);
      bf16x8 kb2l = *reinterpret_cast<const bf16x8*>(&Klo[kr1 + quad * 8]);
      bf16x8 kb3h = *reinterpret_cast<const bf16x8*>(&Khi[kr1 + 32 + quad * 8]);
      bf16x8 kb3l = *reinterpret_cast<const bf16x8*>(&Klo[kr1 + 32 + quad * 8]);
      s1 = __builtin_amdgcn_mfma_f32_16x16x32_bf16(qa0h, kb2h, s1, 0, 0, 0);
      s1 = __builtin_amdgcn_mfma_f32_16x16x32_bf16(qa0h, kb2l, s1, 0, 0, 0);
      s1 = __builtin_amdgcn_mfma_f32_16x16x32_bf16(qa0l, kb2h, s1, 0, 0, 0);
      s1 = __builtin_amdgcn_mfma_f32_16x16x32_bf16(qa1h, kb3h, s1, 0, 0, 0);
      s1 = __builtin_amdgcn_mfma_f32_16x16x32_bf16(qa1h, kb3l, s1, 0, 0, 0);
      s1 = __builtin_amdgcn_mfma_f32_16x16x32_bf16(qa1l, kb3h, s1, 0, 0, 0);
    }
    float alpha[4];
    #pragma unroll
    for (int r = 0; r < 4; ++r) {
      float v0 = s0[r] * scale, v1 = s1[r] * scale;
      float mt = fmaxf(v0, v1);
      mt = fmaxf(mt, __shfl_xor(mt, 1));
      mt = fmaxf(mt, __shfl_xor(mt, 2));
      mt = fmaxf(mt, __shfl_xor(mt, 4));
      mt = fmaxf(mt, __shfl_xor(mt, 8));
      float mn = fmaxf(m_i[r], mt);
      float a  = __expf(m_i[r] - mn);
      float p0 = __expf(v0 - mn);
      float p1 = __expf(v1 - mn);
      float ps = p0 + p1;
      ps += __shfl_xor(ps, 1);
      ps += __shfl_xor(ps, 2);
      ps += __shfl_xor(ps, 4);
      ps += __shfl_xor(ps, 8);
      l_i[r] = l_i[r] * a + ps;
      m_i[r] = mn;
      alpha[r] = a;
      bf16_t hh, ll;
      split2(p0, hh, ll);
      sPh[quad * 4 + r][lm] = hh;      sPl[quad * 4 + r][lm] = ll;
      split2(p1, hh, ll);
      sPh[quad * 4 + r][16 + lm] = hh; sPl[quad * 4 + r][16 + lm] = ll;
    }
    __syncthreads();
    bf16x8 pah = *reinterpret_cast<const bf16x8*>(&sPh[lm][quad * 8]);
    bf16x8 pal = *reinterpret_cast<const bf16x8*>(&sPl[lm][quad * 8]);
    #pragma unroll
    for (int ni = 0; ni < 4; ++ni)
      #pragma unroll
      for (int r = 0; r < 4; ++r) o[ni][r] *= alpha[r];
    #pragma unroll
    for (int ni = 0; ni < 4; ++ni) {
      size_t vo = ((size_t)(b * D_DIM + h * 64 + ni * 16 + lm)) * L_DIM + kt + quad * 8;
      const bf16x8 vbh = *reinterpret_cast<const bf16x8*>(&VThi[vo]);
      const bf16x8 vbl = *reinterpret_cast<const bf16x8*>(&VTlo[vo]);
      o[ni] = __builtin_amdgcn_mfma_f32_16x16x32_bf16(pah, vbh, o[ni], 0, 0, 0);
      o[ni] = __builtin_amdgcn_mfma_f32_16x16x32_bf16(pah, vbl, o[ni], 0, 0, 0);
      o[ni] = __builtin_amdgcn_mfma_f32_16x16x32_bf16(pal, vbh, o[ni], 0, 0, 0);
    }
    __syncthreads();
  }

  #pragma unroll
  for (int r = 0; r < 4; ++r) {
    int s2 = sel[bh * SLOTS + qt * 16 + quad * 4 + r];
    if (s2 >= 0) {
      float inv = (l_i[r] > 0.f) ? (1.0f / l_i[r]) : 0.f;
      size_t orow = ((size_t)(b * L_DIM + s2)) * D_DIM + h * 64;
      #pragma unroll
      for (int ni = 0; ni < 4; ++ni) {
        bf16_t hh, ll;
        split2(o[ni][r] * inv, hh, ll);
        AOhi[orow + ni * 16 + lm] = hh;
        AOlo[orow + ni * 16 + lm] = ll;
      }
    }
  }
}

// ---------------------------------------------------------------------------
extern "C" void kernel_launch(void* const* d_in, const int* in_sizes, int n_in,
                              void* d_out, int out_size, void* d_ws, size_t ws_size,
                              hipStream_t stream) {
  const float* x  = (const float*)d_in[0];
  const float* Wq = (const float*)d_in[1];
  const float* bq = (const float*)d_in[2];
  const float* Wk = (const float*)d_in[3];
  const float* bk = (const float*)d_in[4];
  const float* Wv = (const float*)d_in[5];
  const float* bv = (const float*)d_in[6];
  const float* Wo = (const float*)d_in[7];
  const float* bo = (const float*)d_in[8];
  float* out = (float*)d_out;

  const size_t MB = 1u << 20;
  char* ws = (char*)d_ws;
  bf16_t* Qhi  = (bf16_t*)(ws);             // 8 MB
  bf16_t* Qlo  = (bf16_t*)(ws + 8  * MB);   // 8 MB
  bf16_t* VThi = (bf16_t*)(ws + 16 * MB);   // 8 MB
  bf16_t* VTlo = (bf16_t*)(ws + 24 * MB);   // 8 MB
  bf16_t* AOhi = (bf16_t*)(ws + 32 * MB);   // 8 MB
  bf16_t* AOlo = (bf16_t*)(ws + 40 * MB);   // 8 MB
  float*  norms = (float*)(ws + 48 * MB);   // 256 KB
  int*    sel   = (int*)(ws + 48 * MB + (256u << 10)); // 52 KB
  // K pair lives in d_out (16 MB f32) — dead until gemm_out rewrites it all.
  bf16_t* Khi = (bf16_t*)d_out;
  bf16_t* Klo = Khi + (size_t)M_DIM * D_DIM;

  dim3 blk(256);
  gemm_qkv<<<dim3(8, 32, 3), blk, 0, stream>>>(x, Wq, Wk, Wv, bq, bk, bv,
                                               Qhi, Qlo, Khi, Klo, VThi, VTlo, norms);
  topk_kernel<<<dim3(32), blk, 0, stream>>>(norms, sel);
  meanfill_kernel<<<dim3(32, 8), blk, 0, stream>>>(VThi, VTlo, AOhi, AOlo);
  attn_kernel<<<dim3(32 * 26), dim3(64), 0, stream>>>(Qhi, Qlo, Khi, Klo, VThi, VTlo, sel, AOhi, AOlo);
  gemm_out<<<dim3(8, 32), blk, 0, stream>>>(AOhi, AOlo, Wo, bo, out);
}

// Round 4
// 508.300 us; speedup vs baseline: 1.1361x; 1.1361x over previous
//
#include <hip/hip_runtime.h>
#include <hip/hip_bf16.h>
#include <math.h>

typedef __bf16 bf16_t;
typedef __bf16 bf16x8 __attribute__((ext_vector_type(8)));
typedef __bf16 bf16x4 __attribute__((ext_vector_type(4)));
typedef float  f32x4  __attribute__((ext_vector_type(4)));

#define L_DIM 2048
#define D_DIM 1024
#define H_DIM 16
#define M_DIM 4096
#define KTOP 409
#define SLOTS 448    // 7 * 64, padded (sel = -1 beyond KTOP)
#define KSPLIT 4
#define KCHUNK 512   // L_DIM / KSPLIT

// split f32 into bf16 hi + bf16 lo (a ~= hi + lo, |a-hi-lo| <= 2^-18 |a|)
__device__ __forceinline__ void split2(float a, bf16_t& h, bf16_t& l) {
  h = (bf16_t)a;
  l = (bf16_t)(a - (float)h);
}

// ---------------------------------------------------------------------------
// QKV GEMM, f32 in, split-bf16 3-product MFMA, f32 accumulate.
// z=0 -> Q (hi/lo) + fp32 per-head row norms; z=1 -> K (hi/lo);
// z=2 -> V transposed: VT[(b*1024+col)*2048 + l] (hi/lo).
// ---------------------------------------------------------------------------
__global__ __launch_bounds__(256) void gemm_qkv(
    const float* __restrict__ A,
    const float* __restrict__ W0, const float* __restrict__ W1, const float* __restrict__ W2,
    const float* __restrict__ b0, const float* __restrict__ b1, const float* __restrict__ b2,
    bf16_t* __restrict__ Qhi, bf16_t* __restrict__ Qlo,
    bf16_t* __restrict__ Khi, bf16_t* __restrict__ Klo,
    bf16_t* __restrict__ Vhi, bf16_t* __restrict__ Vlo,
    float* __restrict__ norms)
{
  const int z = blockIdx.z;
  const float* W    = (z == 0) ? W0 : (z == 1) ? W1 : W2;
  const float* bias = (z == 0) ? b0 : (z == 1) ? b1 : b2;
  bf16_t* Chi = (z == 0) ? Qhi : (z == 1) ? Khi : Vhi;
  bf16_t* Clo = (z == 0) ? Qlo : (z == 1) ? Klo : Vlo;
  const bool do_norm = (z == 0);
  const bool trans   = (z == 2);

  const int n0   = blockIdx.x * 128;
  const int row0 = blockIdx.y * 128;

  __shared__ __align__(16) bf16_t sAhi[128][40];
  __shared__ __align__(16) bf16_t sAlo[128][40];
  __shared__ __align__(16) bf16_t sBhi[128][40];
  __shared__ __align__(16) bf16_t sBlo[128][40];

  const int tid  = threadIdx.x;
  const int lane = tid & 63;
  const int wave = tid >> 6;
  const int wr = wave >> 1, wc = wave & 1;
  const int lm = lane & 15, quad = lane >> 4;

  const f32x4 vzero = {0.f, 0.f, 0.f, 0.f};
  f32x4 acc[4][4];
  #pragma unroll
  for (int mi = 0; mi < 4; ++mi)
    #pragma unroll
    for (int ni = 0; ni < 4; ++ni) acc[mi][ni] = vzero;

  for (int k0 = 0; k0 < D_DIM; k0 += 32) {
    __syncthreads();
    #pragma unroll
    for (int i = 0; i < 4; ++i) {
      int t  = tid + i * 256;     // 0..1023
      int rr = t >> 3;            // 0..127
      int cc = (t & 7) * 4;       // 0..28
      f32x4 av = *reinterpret_cast<const f32x4*>(&A[(size_t)(row0 + rr) * D_DIM + k0 + cc]);
      f32x4 wv = *reinterpret_cast<const f32x4*>(&W[(size_t)(n0  + rr) * D_DIM + k0 + cc]);
      bf16x4 ah, al, wh, wl;
      #pragma unroll
      for (int j = 0; j < 4; ++j) {
        bf16_t h, l;
        split2(av[j], h, l); ah[j] = h; al[j] = l;
        split2(wv[j], h, l); wh[j] = h; wl[j] = l;
      }
      *reinterpret_cast<bf16x4*>(&sAhi[rr][cc]) = ah;
      *reinterpret_cast<bf16x4*>(&sAlo[rr][cc]) = al;
      *reinterpret_cast<bf16x4*>(&sBhi[rr][cc]) = wh;
      *reinterpret_cast<bf16x4*>(&sBlo[rr][cc]) = wl;
    }
    __syncthreads();
    bf16x8 afh[4], afl[4], bfh[4], bfl[4];
    #pragma unroll
    for (int mi = 0; mi < 4; ++mi) {
      afh[mi] = *reinterpret_cast<const bf16x8*>(&sAhi[wr * 64 + mi * 16 + lm][quad * 8]);
      afl[mi] = *reinterpret_cast<const bf16x8*>(&sAlo[wr * 64 + mi * 16 + lm][quad * 8]);
    }
    #pragma unroll
    for (int ni = 0; ni < 4; ++ni) {
      bfh[ni] = *reinterpret_cast<const bf16x8*>(&sBhi[wc * 64 + ni * 16 + lm][quad * 8]);
      bfl[ni] = *reinterpret_cast<const bf16x8*>(&sBlo[wc * 64 + ni * 16 + lm][quad * 8]);
    }
    #pragma unroll
    for (int mi = 0; mi < 4; ++mi)
      #pragma unroll
      for (int ni = 0; ni < 4; ++ni) {
        acc[mi][ni] = __builtin_amdgcn_mfma_f32_16x16x32_bf16(afh[mi], bfh[ni], acc[mi][ni], 0, 0, 0);
        acc[mi][ni] = __builtin_amdgcn_mfma_f32_16x16x32_bf16(afh[mi], bfl[ni], acc[mi][ni], 0, 0, 0);
        acc[mi][ni] = __builtin_amdgcn_mfma_f32_16x16x32_bf16(afl[mi], bfh[ni], acc[mi][ni], 0, 0, 0);
      }
  }

  float bv[4];
  #pragma unroll
  for (int ni = 0; ni < 4; ++ni) bv[ni] = bias[n0 + wc * 64 + ni * 16 + lm];
  #pragma unroll
  for (int mi = 0; mi < 4; ++mi)
    #pragma unroll
    for (int ni = 0; ni < 4; ++ni)
      #pragma unroll
      for (int r = 0; r < 4; ++r) acc[mi][ni][r] += bv[ni];

  if (do_norm) {
    const int h = (n0 + wc * 64) >> 6;
    #pragma unroll
    for (int mi = 0; mi < 4; ++mi)
      #pragma unroll
      for (int r = 0; r < 4; ++r) {
        float s = 0.f;
        #pragma unroll
        for (int ni = 0; ni < 4; ++ni) { float v = acc[mi][ni][r]; s += v * v; }
        s += __shfl_xor(s, 1); s += __shfl_xor(s, 2);
        s += __shfl_xor(s, 4); s += __shfl_xor(s, 8);
        if (lm == 0) {
          int row = row0 + wr * 64 + mi * 16 + quad * 4 + r;
          int bb = row >> 11, ll = row & (L_DIM - 1);
          norms[(bb * H_DIM + h) * L_DIM + ll] = s;
        }
      }
  }

  if (!trans) {
    #pragma unroll
    for (int mi = 0; mi < 4; ++mi)
      #pragma unroll
      for (int r = 0; r < 4; ++r) {
        int row = row0 + wr * 64 + mi * 16 + quad * 4 + r;
        #pragma unroll
        for (int ni = 0; ni < 4; ++ni) {
          int col = n0 + wc * 64 + ni * 16 + lm;
          bf16_t h, l;
          split2(acc[mi][ni][r], h, l);
          Chi[(size_t)row * D_DIM + col] = h;
          Clo[(size_t)row * D_DIM + col] = l;
        }
      }
  } else {
    #pragma unroll
    for (int mi = 0; mi < 4; ++mi) {
      int rbase = row0 + wr * 64 + mi * 16 + quad * 4;
      int bb = rbase >> 11, l0 = rbase & (L_DIM - 1);
      #pragma unroll
      for (int ni = 0; ni < 4; ++ni) {
        int col = n0 + wc * 64 + ni * 16 + lm;
        bf16x4 wh, wl;
        #pragma unroll
        for (int r = 0; r < 4; ++r) {
          bf16_t h, l;
          split2(acc[mi][ni][r], h, l);
          wh[r] = h; wl[r] = l;
        }
        size_t o = ((size_t)(bb * D_DIM + col)) * L_DIM + l0;
        *reinterpret_cast<bf16x4*>(&Vhi[o]) = wh;
        *reinterpret_cast<bf16x4*>(&Vlo[o]) = wl;
      }
    }
  }
}

// ---------------------------------------------------------------------------
// Output projection: A = AO as bf16 hi/lo pair, W = Wo f32, C = f32 out.
// ---------------------------------------------------------------------------
__global__ __launch_bounds__(256) void gemm_out(
    const bf16_t* __restrict__ Ahi, const bf16_t* __restrict__ Alo,
    const float* __restrict__ W, const float* __restrict__ bias,
    float* __restrict__ C)
{
  const int n0   = blockIdx.x * 128;
  const int row0 = blockIdx.y * 128;

  __shared__ __align__(16) bf16_t sAhi[128][40];
  __shared__ __align__(16) bf16_t sAlo[128][40];
  __shared__ __align__(16) bf16_t sBhi[128][40];
  __shared__ __align__(16) bf16_t sBlo[128][40];

  const int tid  = threadIdx.x;
  const int lane = tid & 63;
  const int wave = tid >> 6;
  const int wr = wave >> 1, wc = wave & 1;
  const int lm = lane & 15, quad = lane >> 4;

  const f32x4 vzero = {0.f, 0.f, 0.f, 0.f};
  f32x4 acc[4][4];
  #pragma unroll
  for (int mi = 0; mi < 4; ++mi)
    #pragma unroll
    for (int ni = 0; ni < 4; ++ni) acc[mi][ni] = vzero;

  for (int k0 = 0; k0 < D_DIM; k0 += 32) {
    __syncthreads();
    #pragma unroll
    for (int i = 0; i < 2; ++i) {
      int t  = tid + i * 256;
      int rr = t >> 2;
      int cc = (t & 3) * 8;
      size_t idx = (size_t)(row0 + rr) * D_DIM + k0 + cc;
      *reinterpret_cast<bf16x8*>(&sAhi[rr][cc]) = *reinterpret_cast<const bf16x8*>(&Ahi[idx]);
      *reinterpret_cast<bf16x8*>(&sAlo[rr][cc]) = *reinterpret_cast<const bf16x8*>(&Alo[idx]);
    }
    #pragma unroll
    for (int i = 0; i < 4; ++i) {
      int t  = tid + i * 256;
      int rr = t >> 3;
      int cc = (t & 7) * 4;
      f32x4 wv = *reinterpret_cast<const f32x4*>(&W[(size_t)(n0 + rr) * D_DIM + k0 + cc]);
      bf16x4 wh, wl;
      #pragma unroll
      for (int j = 0; j < 4; ++j) { bf16_t h, l; split2(wv[j], h, l); wh[j] = h; wl[j] = l; }
      *reinterpret_cast<bf16x4*>(&sBhi[rr][cc]) = wh;
      *reinterpret_cast<bf16x4*>(&sBlo[rr][cc]) = wl;
    }
    __syncthreads();
    bf16x8 afh[4], afl[4], bfh[4], bfl[4];
    #pragma unroll
    for (int mi = 0; mi < 4; ++mi) {
      afh[mi] = *reinterpret_cast<const bf16x8*>(&sAhi[wr * 64 + mi * 16 + lm][quad * 8]);
      afl[mi] = *reinterpret_cast<const bf16x8*>(&sAlo[wr * 64 + mi * 16 + lm][quad * 8]);
    }
    #pragma unroll
    for (int ni = 0; ni < 4; ++ni) {
      bfh[ni] = *reinterpret_cast<const bf16x8*>(&sBhi[wc * 64 + ni * 16 + lm][quad * 8]);
      bfl[ni] = *reinterpret_cast<const bf16x8*>(&sBlo[wc * 64 + ni * 16 + lm][quad * 8]);
    }
    #pragma unroll
    for (int mi = 0; mi < 4; ++mi)
      #pragma unroll
      for (int ni = 0; ni < 4; ++ni) {
        acc[mi][ni] = __builtin_amdgcn_mfma_f32_16x16x32_bf16(afh[mi], bfh[ni], acc[mi][ni], 0, 0, 0);
        acc[mi][ni] = __builtin_amdgcn_mfma_f32_16x16x32_bf16(afh[mi], bfl[ni], acc[mi][ni], 0, 0, 0);
        acc[mi][ni] = __builtin_amdgcn_mfma_f32_16x16x32_bf16(afl[mi], bfh[ni], acc[mi][ni], 0, 0, 0);
      }
  }

  float bv[4];
  #pragma unroll
  for (int ni = 0; ni < 4; ++ni) bv[ni] = bias[n0 + wc * 64 + ni * 16 + lm];
  #pragma unroll
  for (int mi = 0; mi < 4; ++mi)
    #pragma unroll
    for (int r = 0; r < 4; ++r) {
      int row = row0 + wr * 64 + mi * 16 + quad * 4 + r;
      #pragma unroll
      for (int ni = 0; ni < 4; ++ni) {
        int col = n0 + wc * 64 + ni * 16 + lm;
        C[(size_t)row * D_DIM + col] = acc[mi][ni][r] + bv[ni];
      }
    }
}

// ---------------------------------------------------------------------------
// Exact top-409 per (b,h): bitonic sort (norm desc, idx asc) = lax.top_k order.
// Writes SLOTS=448 entries (-1 padding beyond KTOP).
// ---------------------------------------------------------------------------
__global__ __launch_bounds__(256) void topk_kernel(
    const float* __restrict__ norms, int* __restrict__ sel)
{
  const int bh = blockIdx.x;
  __shared__ __align__(16) float val[L_DIM];
  __shared__ __align__(16) int   idx[L_DIM];
  const int t = threadIdx.x;
  for (int i = t; i < L_DIM; i += 256) {
    val[i] = norms[bh * L_DIM + i];
    idx[i] = i;
  }
  __syncthreads();
  for (int k = 2; k <= L_DIM; k <<= 1) {
    for (int j = k >> 1; j > 0; j >>= 1) {
      for (int i = t; i < L_DIM; i += 256) {
        int ixj = i ^ j;
        if (ixj > i) {
          float v1 = val[i], v2 = val[ixj];
          int   i1 = idx[i], i2 = idx[ixj];
          bool up = ((i & k) == 0);
          bool sw = up ? ((v2 > v1) || (v2 == v1 && i2 < i1))
                       : ((v1 > v2) || (v1 == v2 && i1 < i2));
          if (sw) { val[i] = v2; val[ixj] = v1; idx[i] = i2; idx[ixj] = i1; }
        }
      }
      __syncthreads();
    }
  }
  for (int i = t; i < SLOTS; i += 256)
    sel[bh * SLOTS + i] = (i < KTOP) ? idx[i] : -1;
}

// ---------------------------------------------------------------------------
// K-split flash attention over selected queries. Block = 4 waves, each wave
// owns 16 query slots; block covers keys [ks*512, ks*512+512). No softmax max
// (scores bounded, f32 exp safe); l reduced after the K-loop. Writes
// unnormalized partial (l, o) per ksplit chunk.
// blockIdx = bh + 32*(qc + 7*ks) so same-bh blocks share an XCD (%8 affinity).
// ---------------------------------------------------------------------------
__global__ __launch_bounds__(256) void attn_kernel(
    const bf16_t* __restrict__ Qhi, const bf16_t* __restrict__ Qlo,
    const bf16_t* __restrict__ Khi, const bf16_t* __restrict__ Klo,
    const bf16_t* __restrict__ VThi, const bf16_t* __restrict__ VTlo,
    const int* __restrict__ sel,
    float* __restrict__ Ol, float* __restrict__ Oo)
{
  const int bx = blockIdx.x;
  const int bh = bx & 31;
  const int t2 = bx >> 5;
  const int qc = t2 % 7;
  const int ks = t2 / 7;
  const int b = bh >> 4, h = bh & 15;
  const int wave = threadIdx.x >> 6;
  const int lane = threadIdx.x & 63;
  const int lm = lane & 15, quad = lane >> 4;

  __shared__ __align__(16) bf16_t sPh[4][16][40];

  const int qbase = qc * 64 + wave * 16;
  const int qi = sel[bh * SLOTS + qbase + lm];
  const size_t qo = ((size_t)(b * L_DIM + (qi >= 0 ? qi : 0))) * D_DIM + h * 64;
  const bf16x8 qa0h = *reinterpret_cast<const bf16x8*>(&Qhi[qo + quad * 8]);
  const bf16x8 qa0l = *reinterpret_cast<const bf16x8*>(&Qlo[qo + quad * 8]);
  const bf16x8 qa1h = *reinterpret_cast<const bf16x8*>(&Qhi[qo + 32 + quad * 8]);
  const bf16x8 qa1l = *reinterpret_cast<const bf16x8*>(&Qlo[qo + 32 + quad * 8]);

  const f32x4 vzero = {0.f, 0.f, 0.f, 0.f};
  float l_l[4] = {0.f, 0.f, 0.f, 0.f};   // per-lane partial sum of p
  f32x4 o[4];
  #pragma unroll
  for (int ni = 0; ni < 4; ++ni) o[ni] = vzero;

  const float scale = 0.125f;
  const size_t kbase = (size_t)(b * L_DIM) * D_DIM + h * 64;
  const int key0 = ks * KCHUNK;

  for (int kt = 0; kt < KCHUNK; kt += 32) {
    f32x4 s0 = vzero, s1 = vzero;
    {
      size_t kr0 = kbase + (size_t)(key0 + kt + lm) * D_DIM;
      bf16x8 kb0h = *reinterpret_cast<const bf16x8*>(&Khi[kr0 + quad * 8]);
      bf16x8 kb0l = *reinterpret_cast<const bf16x8*>(&Klo[kr0 + quad * 8]);
      bf16x8 kb1h = *reinterpret_cast<const bf16x8*>(&Khi[kr0 + 32 + quad * 8]);
      bf16x8 kb1l = *reinterpret_cast<const bf16x8*>(&Klo[kr0 + 32 + quad * 8]);
      s0 = __builtin_amdgcn_mfma_f32_16x16x32_bf16(qa0h, kb0h, s0, 0, 0, 0);
      s0 = __builtin_amdgcn_mfma_f32_16x16x32_bf16(qa0h, kb0l, s0, 0, 0, 0);
      s0 = __builtin_amdgcn_mfma_f32_16x16x32_bf16(qa0l, kb0h, s0, 0, 0, 0);
      s0 = __builtin_amdgcn_mfma_f32_16x16x32_bf16(qa1h, kb1h, s0, 0, 0, 0);
      s0 = __builtin_amdgcn_mfma_f32_16x16x32_bf16(qa1h, kb1l, s0, 0, 0, 0);
      s0 = __builtin_amdgcn_mfma_f32_16x16x32_bf16(qa1l, kb1h, s0, 0, 0, 0);
      size_t kr1 = kbase + (size_t)(key0 + kt + 16 + lm) * D_DIM;
      bf16x8 kb2h = *reinterpret_cast<const bf16x8*>(&Khi[kr1 + quad * 8]);
      bf16x8 kb2l = *reinterpret_cast<const bf16x8*>(&Klo[kr1 + quad * 8]);
      bf16x8 kb3h = *reinterpret_cast<const bf16x8*>(&Khi[kr1 + 32 + quad * 8]);
      bf16x8 kb3l = *reinterpret_cast<const bf16x8*>(&Klo[kr1 + 32 + quad * 8]);
      s1 = __builtin_amdgcn_mfma_f32_16x16x32_bf16(qa0h, kb2h, s1, 0, 0, 0);
      s1 = __builtin_amdgcn_mfma_f32_16x16x32_bf16(qa0h, kb2l, s1, 0, 0, 0);
      s1 = __builtin_amdgcn_mfma_f32_16x16x32_bf16(qa0l, kb2h, s1, 0, 0, 0);
      s1 = __builtin_amdgcn_mfma_f32_16x16x32_bf16(qa1h, kb3h, s1, 0, 0, 0);
      s1 = __builtin_amdgcn_mfma_f32_16x16x32_bf16(qa1h, kb3l, s1, 0, 0, 0);
      s1 = __builtin_amdgcn_mfma_f32_16x16x32_bf16(qa1l, kb3h, s1, 0, 0, 0);
    }
    #pragma unroll
    for (int r = 0; r < 4; ++r) {
      float p0 = __expf(s0[r] * scale);
      float p1 = __expf(s1[r] * scale);
      l_l[r] += p0 + p1;
      sPh[wave][quad * 4 + r][lm]      = (bf16_t)p0;
      sPh[wave][quad * 4 + r][16 + lm] = (bf16_t)p1;
    }
    __syncthreads();
    bf16x8 pah = *reinterpret_cast<const bf16x8*>(&sPh[wave][lm][quad * 8]);
    #pragma unroll
    for (int ni = 0; ni < 4; ++ni) {
      size_t vo = ((size_t)(b * D_DIM + h * 64 + ni * 16 + lm)) * L_DIM + key0 + kt + quad * 8;
      const bf16x8 vbh = *reinterpret_cast<const bf16x8*>(&VThi[vo]);
      const bf16x8 vbl = *reinterpret_cast<const bf16x8*>(&VTlo[vo]);
      o[ni] = __builtin_amdgcn_mfma_f32_16x16x32_bf16(pah, vbh, o[ni], 0, 0, 0);
      o[ni] = __builtin_amdgcn_mfma_f32_16x16x32_bf16(pah, vbl, o[ni], 0, 0, 0);
    }
    __syncthreads();
  }

  // reduce l across the 16 key-lanes (lane bits 0..3)
  #pragma unroll
  for (int r = 0; r < 4; ++r) {
    l_l[r] += __shfl_xor(l_l[r], 1);
    l_l[r] += __shfl_xor(l_l[r], 2);
    l_l[r] += __shfl_xor(l_l[r], 4);
    l_l[r] += __shfl_xor(l_l[r], 8);
  }

  #pragma unroll
  for (int r = 0; r < 4; ++r) {
    int slot = qbase + quad * 4 + r;
    int s2 = sel[bh * SLOTS + slot];
    if (s2 >= 0) {
      size_t gs = (size_t)(bh * SLOTS + slot) * KSPLIT + ks;
      if (lm == 0) Ol[gs] = l_l[r];
      #pragma unroll
      for (int ni = 0; ni < 4; ++ni)
        Oo[gs * 64 + ni * 16 + lm] = o[ni][r];
    }
  }
}

// ---------------------------------------------------------------------------
// Combine ksplit partials: out = (sum o) / (sum l); write AO hi/lo (selected
// rows only — meanfill already filled every row).
// ---------------------------------------------------------------------------
__global__ __launch_bounds__(256) void combine_kernel(
    const float* __restrict__ Ol, const float* __restrict__ Oo,
    const int* __restrict__ sel,
    bf16_t* __restrict__ AOhi, bf16_t* __restrict__ AOlo)
{
  const int bh = blockIdx.x;
  const int b = bh >> 4, h = bh & 15;
  const int chunk = blockIdx.y;     // 0..27 -> 16 slots each
  const int tid = threadIdx.x;
  const int dim = tid & 63;
  const int sl  = tid >> 6;         // 0..3
  #pragma unroll
  for (int p = 0; p < 4; ++p) {
    int slot = chunk * 16 + p * 4 + sl;
    int qi = sel[bh * SLOTS + slot];
    if (qi < 0) continue;
    size_t gs = (size_t)(bh * SLOTS + slot) * KSPLIT;
    float L = Ol[gs] + Ol[gs + 1] + Ol[gs + 2] + Ol[gs + 3];
    float ov = Oo[gs * 64 + dim] + Oo[(gs + 1) * 64 + dim]
             + Oo[(gs + 2) * 64 + dim] + Oo[(gs + 3) * 64 + dim];
    float val = ov / L;
    bf16_t hh, ll;
    split2(val, hh, ll);
    size_t orow = ((size_t)(b * L_DIM + qi)) * D_DIM + h * 64 + dim;
    AOhi[orow] = hh;
    AOlo[orow] = ll;
  }
}

// ---------------------------------------------------------------------------
// mean(V) to EVERY AO row (uniform softmax rows); combine overwrites selected.
// ---------------------------------------------------------------------------
__global__ __launch_bounds__(256) void meanfill_kernel(
    const bf16_t* __restrict__ VThi, const bf16_t* __restrict__ VTlo,
    bf16_t* __restrict__ AOhi, bf16_t* __restrict__ AOlo)
{
  const int bh = blockIdx.x;
  const int b = bh >> 4, h = bh & 15;
  const int t = threadIdx.x;
  __shared__ __align__(16) bf16_t smh[64];
  __shared__ __align__(16) bf16_t sml[64];
  {
    const int hd = t >> 2, part = t & 3;
    size_t base = ((size_t)(b * D_DIM + h * 64 + hd)) * L_DIM;
    float s = 0.f;
    for (int l0 = part * 512; l0 < part * 512 + 512; l0 += 8) {
      bf16x8 vh = *reinterpret_cast<const bf16x8*>(&VThi[base + l0]);
      bf16x8 vl = *reinterpret_cast<const bf16x8*>(&VTlo[base + l0]);
      #pragma unroll
      for (int j = 0; j < 8; ++j) s += (float)vh[j] + (float)vl[j];
    }
    s += __shfl_xor(s, 1);
    s += __shfl_xor(s, 2);
    if (part == 0) {
      bf16_t hh, ll;
      split2(s * (1.0f / (float)L_DIM), hh, ll);
      smh[hd] = hh; sml[hd] = ll;
    }
  }
  __syncthreads();
  const int lbase = blockIdx.y * 256;
  for (int i = t; i < 256 * 64; i += 256) {
    int l = lbase + (i >> 6), hd = i & 63;
    size_t o = ((size_t)(b * L_DIM + l)) * D_DIM + h * 64 + hd;
    AOhi[o] = smh[hd];
    AOlo[o] = sml[hd];
  }
}

// ---------------------------------------------------------------------------
extern "C" void kernel_launch(void* const* d_in, const int* in_sizes, int n_in,
                              void* d_out, int out_size, void* d_ws, size_t ws_size,
                              hipStream_t stream) {
  const float* x  = (const float*)d_in[0];
  const float* Wq = (const float*)d_in[1];
  const float* bq = (const float*)d_in[2];
  const float* Wk = (const float*)d_in[3];
  const float* bk = (const float*)d_in[4];
  const float* Wv = (const float*)d_in[5];
  const float* bv = (const float*)d_in[6];
  const float* Wo = (const float*)d_in[7];
  const float* bo = (const float*)d_in[8];
  float* out = (float*)d_out;

  // ws layout (total <= 48 MB):
  //   [0,16M)   Q hi/lo  — reused as AO hi/lo after attn (meanfill runs after attn)
  //   [16,32M)  VT hi/lo
  //   32M       norms (256 KB)
  //   32M+256K  sel (57 KB)
  //   32M+320K  Ol (229 KB)
  //   33M       Oo (14.0 MB)
  // K hi/lo lives in d_out (16 MB) — dead until gemm_out rewrites it all.
  const size_t MB = 1u << 20;
  char* ws = (char*)d_ws;
  bf16_t* Qhi  = (bf16_t*)(ws);
  bf16_t* Qlo  = (bf16_t*)(ws + 8  * MB);
  bf16_t* VThi = (bf16_t*)(ws + 16 * MB);
  bf16_t* VTlo = (bf16_t*)(ws + 24 * MB);
  float*  norms = (float*)(ws + 32 * MB);
  int*    sel   = (int*)(ws + 32 * MB + (256u << 10));
  float*  Ol    = (float*)(ws + 32 * MB + (320u << 10));
  float*  Oo    = (float*)(ws + 33 * MB);
  bf16_t* AOhi = Qhi;
  bf16_t* AOlo = Qlo;
  bf16_t* Khi = (bf16_t*)d_out;
  bf16_t* Klo = Khi + (size_t)M_DIM * D_DIM;

  dim3 blk(256);
  gemm_qkv<<<dim3(8, 32, 3), blk, 0, stream>>>(x, Wq, Wk, Wv, bq, bk, bv,
                                               Qhi, Qlo, Khi, Klo, VThi, VTlo, norms);
  topk_kernel<<<dim3(32), blk, 0, stream>>>(norms, sel);
  attn_kernel<<<dim3(32 * 7 * KSPLIT), blk, 0, stream>>>(Qhi, Qlo, Khi, Klo,
                                                         VThi, VTlo, sel, Ol, Oo);
  meanfill_kernel<<<dim3(32, 8), blk, 0, stream>>>(VThi, VTlo, AOhi, AOlo);
  combine_kernel<<<dim3(32, 28), blk, 0, stream>>>(Ol, Oo, sel, AOhi, AOlo);
  gemm_out<<<dim3(8, 32), blk, 0, stream>>>(AOhi, AOlo, Wo, bo, out);
}

// Round 5
// 343.408 us; speedup vs baseline: 1.6816x; 1.4802x over previous
//
#include <hip/hip_runtime.h>
#include <hip/hip_bf16.h>
#include <math.h>

typedef __bf16 bf16_t;
typedef __bf16 bf16x8 __attribute__((ext_vector_type(8)));
typedef __bf16 bf16x4 __attribute__((ext_vector_type(4)));
typedef float  f32x4  __attribute__((ext_vector_type(4)));

#define L_DIM 2048
#define D_DIM 1024
#define H_DIM 16
#define M_DIM 4096
#define KTOP 409
#define SLOTS 448    // 7 * 64, padded (sel = -1 beyond KTOP)
#define KSPLIT 4
#define KCHUNK 512   // L_DIM / KSPLIT

// split f32 into bf16 hi + bf16 lo (a ~= hi + lo)
__device__ __forceinline__ void split2(float a, bf16_t& h, bf16_t& l) {
  h = (bf16_t)a;
  l = (bf16_t)(a - (float)h);
}

// ---------------------------------------------------------------------------
// Q projection: split-bf16 3-product MFMA (f32-accurate accumulators feed the
// top-k norms — rank gap ~3e-4 relative demands it). Stores Qhi (single bf16)
// for attention + f32 per-(b,h) row norms.
// ---------------------------------------------------------------------------
__global__ __launch_bounds__(256) void gemm_q(
    const float* __restrict__ A, const float* __restrict__ W,
    const float* __restrict__ bias,
    bf16_t* __restrict__ Qhi, float* __restrict__ norms)
{
  const int n0   = blockIdx.x * 128;
  const int row0 = blockIdx.y * 128;

  __shared__ __align__(16) bf16_t sAhi[128][40];
  __shared__ __align__(16) bf16_t sAlo[128][40];
  __shared__ __align__(16) bf16_t sBhi[128][40];
  __shared__ __align__(16) bf16_t sBlo[128][40];

  const int tid  = threadIdx.x;
  const int lane = tid & 63;
  const int wave = tid >> 6;
  const int wr = wave >> 1, wc = wave & 1;
  const int lm = lane & 15, quad = lane >> 4;

  const f32x4 vzero = {0.f, 0.f, 0.f, 0.f};
  f32x4 acc[4][4];
  #pragma unroll
  for (int mi = 0; mi < 4; ++mi)
    #pragma unroll
    for (int ni = 0; ni < 4; ++ni) acc[mi][ni] = vzero;

  for (int k0 = 0; k0 < D_DIM; k0 += 32) {
    __syncthreads();
    #pragma unroll
    for (int i = 0; i < 4; ++i) {
      int t  = tid + i * 256;
      int rr = t >> 3;
      int cc = (t & 7) * 4;
      f32x4 av = *reinterpret_cast<const f32x4*>(&A[(size_t)(row0 + rr) * D_DIM + k0 + cc]);
      f32x4 wv = *reinterpret_cast<const f32x4*>(&W[(size_t)(n0  + rr) * D_DIM + k0 + cc]);
      bf16x4 ah, al, wh, wl;
      #pragma unroll
      for (int j = 0; j < 4; ++j) {
        bf16_t h, l;
        split2(av[j], h, l); ah[j] = h; al[j] = l;
        split2(wv[j], h, l); wh[j] = h; wl[j] = l;
      }
      *reinterpret_cast<bf16x4*>(&sAhi[rr][cc]) = ah;
      *reinterpret_cast<bf16x4*>(&sAlo[rr][cc]) = al;
      *reinterpret_cast<bf16x4*>(&sBhi[rr][cc]) = wh;
      *reinterpret_cast<bf16x4*>(&sBlo[rr][cc]) = wl;
    }
    __syncthreads();
    bf16x8 afh[4], afl[4], bfh[4], bfl[4];
    #pragma unroll
    for (int mi = 0; mi < 4; ++mi) {
      afh[mi] = *reinterpret_cast<const bf16x8*>(&sAhi[wr * 64 + mi * 16 + lm][quad * 8]);
      afl[mi] = *reinterpret_cast<const bf16x8*>(&sAlo[wr * 64 + mi * 16 + lm][quad * 8]);
    }
    #pragma unroll
    for (int ni = 0; ni < 4; ++ni) {
      bfh[ni] = *reinterpret_cast<const bf16x8*>(&sBhi[wc * 64 + ni * 16 + lm][quad * 8]);
      bfl[ni] = *reinterpret_cast<const bf16x8*>(&sBlo[wc * 64 + ni * 16 + lm][quad * 8]);
    }
    #pragma unroll
    for (int mi = 0; mi < 4; ++mi)
      #pragma unroll
      for (int ni = 0; ni < 4; ++ni) {
        acc[mi][ni] = __builtin_amdgcn_mfma_f32_16x16x32_bf16(afh[mi], bfh[ni], acc[mi][ni], 0, 0, 0);
        acc[mi][ni] = __builtin_amdgcn_mfma_f32_16x16x32_bf16(afh[mi], bfl[ni], acc[mi][ni], 0, 0, 0);
        acc[mi][ni] = __builtin_amdgcn_mfma_f32_16x16x32_bf16(afl[mi], bfh[ni], acc[mi][ni], 0, 0, 0);
      }
  }

  float bv[4];
  #pragma unroll
  for (int ni = 0; ni < 4; ++ni) bv[ni] = bias[n0 + wc * 64 + ni * 16 + lm];
  #pragma unroll
  for (int mi = 0; mi < 4; ++mi)
    #pragma unroll
    for (int ni = 0; ni < 4; ++ni)
      #pragma unroll
      for (int r = 0; r < 4; ++r) acc[mi][ni][r] += bv[ni];

  // f32 row-norms per head (wave = one head's 64 cols)
  const int h = (n0 + wc * 64) >> 6;
  #pragma unroll
  for (int mi = 0; mi < 4; ++mi)
    #pragma unroll
    for (int r = 0; r < 4; ++r) {
      float s = 0.f;
      #pragma unroll
      for (int ni = 0; ni < 4; ++ni) { float v = acc[mi][ni][r]; s += v * v; }
      s += __shfl_xor(s, 1); s += __shfl_xor(s, 2);
      s += __shfl_xor(s, 4); s += __shfl_xor(s, 8);
      if (lm == 0) {
        int row = row0 + wr * 64 + mi * 16 + quad * 4 + r;
        int bb = row >> 11, ll = row & (L_DIM - 1);
        norms[(bb * H_DIM + h) * L_DIM + ll] = s;
      }
    }

  #pragma unroll
  for (int mi = 0; mi < 4; ++mi)
    #pragma unroll
    for (int r = 0; r < 4; ++r) {
      int row = row0 + wr * 64 + mi * 16 + quad * 4 + r;
      #pragma unroll
      for (int ni = 0; ni < 4; ++ni) {
        int col = n0 + wc * 64 + ni * 16 + lm;
        Qhi[(size_t)row * D_DIM + col] = (bf16_t)acc[mi][ni][r];
      }
    }
}

// ---------------------------------------------------------------------------
// K/V projections: single-bf16 (softmax is uniform-ish; 0.4% input rounding
// perturbs final out by only a few e-4). z=0 -> K flat; z=1 -> V transposed.
// ---------------------------------------------------------------------------
__global__ __launch_bounds__(256) void gemm_kv(
    const float* __restrict__ A,
    const float* __restrict__ W0, const float* __restrict__ W1,
    const float* __restrict__ b0, const float* __restrict__ b1,
    bf16_t* __restrict__ Khi, bf16_t* __restrict__ VThi)
{
  const int z = blockIdx.z;
  const float* W    = (z == 0) ? W0 : W1;
  const float* bias = (z == 0) ? b0 : b1;
  const bool trans  = (z == 1);

  const int n0   = blockIdx.x * 128;
  const int row0 = blockIdx.y * 128;

  __shared__ __align__(16) bf16_t sA[128][40];
  __shared__ __align__(16) bf16_t sB[128][40];

  const int tid  = threadIdx.x;
  const int lane = tid & 63;
  const int wave = tid >> 6;
  const int wr = wave >> 1, wc = wave & 1;
  const int lm = lane & 15, quad = lane >> 4;

  const f32x4 vzero = {0.f, 0.f, 0.f, 0.f};
  f32x4 acc[4][4];
  #pragma unroll
  for (int mi = 0; mi < 4; ++mi)
    #pragma unroll
    for (int ni = 0; ni < 4; ++ni) acc[mi][ni] = vzero;

  for (int k0 = 0; k0 < D_DIM; k0 += 32) {
    __syncthreads();
    #pragma unroll
    for (int i = 0; i < 4; ++i) {
      int t  = tid + i * 256;
      int rr = t >> 3;
      int cc = (t & 7) * 4;
      f32x4 av = *reinterpret_cast<const f32x4*>(&A[(size_t)(row0 + rr) * D_DIM + k0 + cc]);
      f32x4 wv = *reinterpret_cast<const f32x4*>(&W[(size_t)(n0  + rr) * D_DIM + k0 + cc]);
      bf16x4 ab, wb;
      #pragma unroll
      for (int j = 0; j < 4; ++j) { ab[j] = (bf16_t)av[j]; wb[j] = (bf16_t)wv[j]; }
      *reinterpret_cast<bf16x4*>(&sA[rr][cc]) = ab;
      *reinterpret_cast<bf16x4*>(&sB[rr][cc]) = wb;
    }
    __syncthreads();
    bf16x8 af[4], bfr[4];
    #pragma unroll
    for (int mi = 0; mi < 4; ++mi)
      af[mi] = *reinterpret_cast<const bf16x8*>(&sA[wr * 64 + mi * 16 + lm][quad * 8]);
    #pragma unroll
    for (int ni = 0; ni < 4; ++ni)
      bfr[ni] = *reinterpret_cast<const bf16x8*>(&sB[wc * 64 + ni * 16 + lm][quad * 8]);
    #pragma unroll
    for (int mi = 0; mi < 4; ++mi)
      #pragma unroll
      for (int ni = 0; ni < 4; ++ni)
        acc[mi][ni] = __builtin_amdgcn_mfma_f32_16x16x32_bf16(af[mi], bfr[ni], acc[mi][ni], 0, 0, 0);
  }

  float bv[4];
  #pragma unroll
  for (int ni = 0; ni < 4; ++ni) bv[ni] = bias[n0 + wc * 64 + ni * 16 + lm];
  #pragma unroll
  for (int mi = 0; mi < 4; ++mi)
    #pragma unroll
    for (int ni = 0; ni < 4; ++ni)
      #pragma unroll
      for (int r = 0; r < 4; ++r) acc[mi][ni][r] += bv[ni];

  if (!trans) {
    #pragma unroll
    for (int mi = 0; mi < 4; ++mi)
      #pragma unroll
      for (int r = 0; r < 4; ++r) {
        int row = row0 + wr * 64 + mi * 16 + quad * 4 + r;
        #pragma unroll
        for (int ni = 0; ni < 4; ++ni) {
          int col = n0 + wc * 64 + ni * 16 + lm;
          Khi[(size_t)row * D_DIM + col] = (bf16_t)acc[mi][ni][r];
        }
      }
  } else {
    #pragma unroll
    for (int mi = 0; mi < 4; ++mi) {
      int rbase = row0 + wr * 64 + mi * 16 + quad * 4;
      int bb = rbase >> 11, l0 = rbase & (L_DIM - 1);
      #pragma unroll
      for (int ni = 0; ni < 4; ++ni) {
        int col = n0 + wc * 64 + ni * 16 + lm;
        bf16x4 wv;
        #pragma unroll
        for (int r = 0; r < 4; ++r) wv[r] = (bf16_t)acc[mi][ni][r];
        *reinterpret_cast<bf16x4*>(&VThi[((size_t)(bb * D_DIM + col)) * L_DIM + l0]) = wv;
      }
    }
  }
}

// ---------------------------------------------------------------------------
// Output projection: AO bf16 x Wo (f32, rounded at staging) -> f32 out.
// ---------------------------------------------------------------------------
__global__ __launch_bounds__(256) void gemm_out(
    const bf16_t* __restrict__ Ahi,
    const float* __restrict__ W, const float* __restrict__ bias,
    float* __restrict__ C)
{
  const int n0   = blockIdx.x * 128;
  const int row0 = blockIdx.y * 128;

  __shared__ __align__(16) bf16_t sA[128][40];
  __shared__ __align__(16) bf16_t sB[128][40];

  const int tid  = threadIdx.x;
  const int lane = tid & 63;
  const int wave = tid >> 6;
  const int wr = wave >> 1, wc = wave & 1;
  const int lm = lane & 15, quad = lane >> 4;

  const f32x4 vzero = {0.f, 0.f, 0.f, 0.f};
  f32x4 acc[4][4];
  #pragma unroll
  for (int mi = 0; mi < 4; ++mi)
    #pragma unroll
    for (int ni = 0; ni < 4; ++ni) acc[mi][ni] = vzero;

  for (int k0 = 0; k0 < D_DIM; k0 += 32) {
    __syncthreads();
    #pragma unroll
    for (int i = 0; i < 2; ++i) {
      int t  = tid + i * 256;
      int rr = t >> 2;
      int cc = (t & 3) * 8;
      *reinterpret_cast<bf16x8*>(&sA[rr][cc]) =
          *reinterpret_cast<const bf16x8*>(&Ahi[(size_t)(row0 + rr) * D_DIM + k0 + cc]);
    }
    #pragma unroll
    for (int i = 0; i < 4; ++i) {
      int t  = tid + i * 256;
      int rr = t >> 3;
      int cc = (t & 7) * 4;
      f32x4 wv = *reinterpret_cast<const f32x4*>(&W[(size_t)(n0 + rr) * D_DIM + k0 + cc]);
      bf16x4 wb;
      #pragma unroll
      for (int j = 0; j < 4; ++j) wb[j] = (bf16_t)wv[j];
      *reinterpret_cast<bf16x4*>(&sB[rr][cc]) = wb;
    }
    __syncthreads();
    bf16x8 af[4], bfr[4];
    #pragma unroll
    for (int mi = 0; mi < 4; ++mi)
      af[mi] = *reinterpret_cast<const bf16x8*>(&sA[wr * 64 + mi * 16 + lm][quad * 8]);
    #pragma unroll
    for (int ni = 0; ni < 4; ++ni)
      bfr[ni] = *reinterpret_cast<const bf16x8*>(&sB[wc * 64 + ni * 16 + lm][quad * 8]);
    #pragma unroll
    for (int mi = 0; mi < 4; ++mi)
      #pragma unroll
      for (int ni = 0; ni < 4; ++ni)
        acc[mi][ni] = __builtin_amdgcn_mfma_f32_16x16x32_bf16(af[mi], bfr[ni], acc[mi][ni], 0, 0, 0);
  }

  float bv[4];
  #pragma unroll
  for (int ni = 0; ni < 4; ++ni) bv[ni] = bias[n0 + wc * 64 + ni * 16 + lm];
  #pragma unroll
  for (int mi = 0; mi < 4; ++mi)
    #pragma unroll
    for (int r = 0; r < 4; ++r) {
      int row = row0 + wr * 64 + mi * 16 + quad * 4 + r;
      #pragma unroll
      for (int ni = 0; ni < 4; ++ni) {
        int col = n0 + wc * 64 + ni * 16 + lm;
        C[(size_t)row * D_DIM + col] = acc[mi][ni][r] + bv[ni];
      }
    }
}

// ---------------------------------------------------------------------------
// Exact top-409 per (b,h): bitonic sort (norm desc, idx asc) = lax.top_k order.
// ---------------------------------------------------------------------------
__global__ __launch_bounds__(1024) void topk_kernel(
    const float* __restrict__ norms, int* __restrict__ sel)
{
  const int bh = blockIdx.x;
  __shared__ __align__(16) float val[L_DIM];
  __shared__ __align__(16) int   idx[L_DIM];
  const int t = threadIdx.x;
  for (int i = t; i < L_DIM; i += 1024) {
    val[i] = norms[bh * L_DIM + i];
    idx[i] = i;
  }
  __syncthreads();
  for (int k = 2; k <= L_DIM; k <<= 1) {
    for (int j = k >> 1; j > 0; j >>= 1) {
      for (int i = t; i < L_DIM; i += 1024) {
        int ixj = i ^ j;
        if (ixj > i) {
          float v1 = val[i], v2 = val[ixj];
          int   i1 = idx[i], i2 = idx[ixj];
          bool up = ((i & k) == 0);
          bool sw = up ? ((v2 > v1) || (v2 == v1 && i2 < i1))
                       : ((v1 > v2) || (v1 == v2 && i1 < i2));
          if (sw) { val[i] = v2; val[ixj] = v1; idx[i] = i2; idx[ixj] = i1; }
        }
      }
      __syncthreads();
    }
  }
  for (int i = t; i < SLOTS; i += 1024)
    sel[bh * SLOTS + i] = (i < KTOP) ? idx[i] : -1;
}

// ---------------------------------------------------------------------------
// K-split flash attention, single-bf16 Q/K/V. Block = 4 waves x 16 q-slots;
// keys [ks*512, +512). No softmax max (scores bounded); l reduced post-loop.
// ---------------------------------------------------------------------------
__global__ __launch_bounds__(256) void attn_kernel(
    const bf16_t* __restrict__ Qhi,
    const bf16_t* __restrict__ Khi,
    const bf16_t* __restrict__ VThi,
    const int* __restrict__ sel,
    float* __restrict__ Ol, float* __restrict__ Oo)
{
  const int bx = blockIdx.x;
  const int bh = bx & 31;
  const int t2 = bx >> 5;
  const int qc = t2 % 7;
  const int ks = t2 / 7;
  const int b = bh >> 4, h = bh & 15;
  const int wave = threadIdx.x >> 6;
  const int lane = threadIdx.x & 63;
  const int lm = lane & 15, quad = lane >> 4;

  __shared__ __align__(16) bf16_t sPh[4][16][40];

  const int qbase = qc * 64 + wave * 16;
  const int qi = sel[bh * SLOTS + qbase + lm];
  const size_t qo = ((size_t)(b * L_DIM + (qi >= 0 ? qi : 0))) * D_DIM + h * 64;
  const bf16x8 qa0 = *reinterpret_cast<const bf16x8*>(&Qhi[qo + quad * 8]);
  const bf16x8 qa1 = *reinterpret_cast<const bf16x8*>(&Qhi[qo + 32 + quad * 8]);

  const f32x4 vzero = {0.f, 0.f, 0.f, 0.f};
  float l_l[4] = {0.f, 0.f, 0.f, 0.f};
  f32x4 o[4];
  #pragma unroll
  for (int ni = 0; ni < 4; ++ni) o[ni] = vzero;

  const float scale = 0.125f;
  const size_t kbase = (size_t)(b * L_DIM) * D_DIM + h * 64;
  const int key0 = ks * KCHUNK;

  for (int kt = 0; kt < KCHUNK; kt += 32) {
    f32x4 s0 = vzero, s1 = vzero;
    {
      size_t kr0 = kbase + (size_t)(key0 + kt + lm) * D_DIM;
      bf16x8 kb0 = *reinterpret_cast<const bf16x8*>(&Khi[kr0 + quad * 8]);
      bf16x8 kb1 = *reinterpret_cast<const bf16x8*>(&Khi[kr0 + 32 + quad * 8]);
      s0 = __builtin_amdgcn_mfma_f32_16x16x32_bf16(qa0, kb0, s0, 0, 0, 0);
      s0 = __builtin_amdgcn_mfma_f32_16x16x32_bf16(qa1, kb1, s0, 0, 0, 0);
      size_t kr1 = kbase + (size_t)(key0 + kt + 16 + lm) * D_DIM;
      bf16x8 kb2 = *reinterpret_cast<const bf16x8*>(&Khi[kr1 + quad * 8]);
      bf16x8 kb3 = *reinterpret_cast<const bf16x8*>(&Khi[kr1 + 32 + quad * 8]);
      s1 = __builtin_amdgcn_mfma_f32_16x16x32_bf16(qa0, kb2, s1, 0, 0, 0);
      s1 = __builtin_amdgcn_mfma_f32_16x16x32_bf16(qa1, kb3, s1, 0, 0, 0);
    }
    #pragma unroll
    for (int r = 0; r < 4; ++r) {
      float p0 = __expf(s0[r] * scale);
      float p1 = __expf(s1[r] * scale);
      l_l[r] += p0 + p1;
      sPh[wave][quad * 4 + r][lm]      = (bf16_t)p0;
      sPh[wave][quad * 4 + r][16 + lm] = (bf16_t)p1;
    }
    __syncthreads();
    bf16x8 pah = *reinterpret_cast<const bf16x8*>(&sPh[wave][lm][quad * 8]);
    #pragma unroll
    for (int ni = 0; ni < 4; ++ni) {
      size_t vo = ((size_t)(b * D_DIM + h * 64 + ni * 16 + lm)) * L_DIM + key0 + kt + quad * 8;
      const bf16x8 vbh = *reinterpret_cast<const bf16x8*>(&VThi[vo]);
      o[ni] = __builtin_amdgcn_mfma_f32_16x16x32_bf16(pah, vbh, o[ni], 0, 0, 0);
    }
    __syncthreads();
  }

  #pragma unroll
  for (int r = 0; r < 4; ++r) {
    l_l[r] += __shfl_xor(l_l[r], 1);
    l_l[r] += __shfl_xor(l_l[r], 2);
    l_l[r] += __shfl_xor(l_l[r], 4);
    l_l[r] += __shfl_xor(l_l[r], 8);
  }

  #pragma unroll
  for (int r = 0; r < 4; ++r) {
    int slot = qbase + quad * 4 + r;
    int s2 = sel[bh * SLOTS + slot];
    if (s2 >= 0) {
      size_t gs = (size_t)(bh * SLOTS + slot) * KSPLIT + ks;
      if (lm == 0) Ol[gs] = l_l[r];
      #pragma unroll
      for (int ni = 0; ni < 4; ++ni)
        Oo[gs * 64 + ni * 16 + lm] = o[ni][r];
    }
  }
}

// ---------------------------------------------------------------------------
// Combine ksplit partials -> AO (selected rows; meanfill covered the rest).
// ---------------------------------------------------------------------------
__global__ __launch_bounds__(256) void combine_kernel(
    const float* __restrict__ Ol, const float* __restrict__ Oo,
    const int* __restrict__ sel, bf16_t* __restrict__ AOhi)
{
  const int bh = blockIdx.x;
  const int b = bh >> 4, h = bh & 15;
  const int chunk = blockIdx.y;
  const int tid = threadIdx.x;
  const int dim = tid & 63;
  const int sl  = tid >> 6;
  #pragma unroll
  for (int p = 0; p < 4; ++p) {
    int slot = chunk * 16 + p * 4 + sl;
    int qi = sel[bh * SLOTS + slot];
    if (qi < 0) continue;
    size_t gs = (size_t)(bh * SLOTS + slot) * KSPLIT;
    float L = Ol[gs] + Ol[gs + 1] + Ol[gs + 2] + Ol[gs + 3];
    float ov = Oo[gs * 64 + dim] + Oo[(gs + 1) * 64 + dim]
             + Oo[(gs + 2) * 64 + dim] + Oo[(gs + 3) * 64 + dim];
    AOhi[((size_t)(b * L_DIM + qi)) * D_DIM + h * 64 + dim] = (bf16_t)(ov / L);
  }
}

// ---------------------------------------------------------------------------
// mean(V) to EVERY AO row; combine overwrites selected rows.
// ---------------------------------------------------------------------------
__global__ __launch_bounds__(256) void meanfill_kernel(
    const bf16_t* __restrict__ VThi, bf16_t* __restrict__ AOhi)
{
  const int bh = blockIdx.x;
  const int b = bh >> 4, h = bh & 15;
  const int t = threadIdx.x;
  __shared__ __align__(16) bf16_t smh[64];
  {
    const int hd = t >> 2, part = t & 3;
    size_t base = ((size_t)(b * D_DIM + h * 64 + hd)) * L_DIM;
    float s = 0.f;
    for (int l0 = part * 512; l0 < part * 512 + 512; l0 += 8) {
      bf16x8 vh = *reinterpret_cast<const bf16x8*>(&VThi[base + l0]);
      #pragma unroll
      for (int j = 0; j < 8; ++j) s += (float)vh[j];
    }
    s += __shfl_xor(s, 1);
    s += __shfl_xor(s, 2);
    if (part == 0) smh[hd] = (bf16_t)(s * (1.0f / (float)L_DIM));
  }
  __syncthreads();
  const int lbase = blockIdx.y * 256;
  for (int i = t; i < 256 * 64; i += 256) {
    int l = lbase + (i >> 6), hd = i & 63;
    AOhi[((size_t)(b * L_DIM + l)) * D_DIM + h * 64 + hd] = smh[hd];
  }
}

// ---------------------------------------------------------------------------
extern "C" void kernel_launch(void* const* d_in, const int* in_sizes, int n_in,
                              void* d_out, int out_size, void* d_ws, size_t ws_size,
                              hipStream_t stream) {
  const float* x  = (const float*)d_in[0];
  const float* Wq = (const float*)d_in[1];
  const float* bq = (const float*)d_in[2];
  const float* Wk = (const float*)d_in[3];
  const float* bk = (const float*)d_in[4];
  const float* Wv = (const float*)d_in[5];
  const float* bv = (const float*)d_in[6];
  const float* Wo = (const float*)d_in[7];
  const float* bo = (const float*)d_in[8];
  float* out = (float*)d_out;

  // ws layout (~31.5 MB): Qhi (reused as AO after attn) | VThi | norms | sel | Ol | Oo
  // Khi lives in d_out (8 of 16 MB) — dead until gemm_out rewrites all of d_out.
  const size_t MB = 1u << 20;
  char* ws = (char*)d_ws;
  bf16_t* Qhi  = (bf16_t*)(ws);                        // 8 MB
  bf16_t* VThi = (bf16_t*)(ws + 8 * MB);               // 8 MB
  float*  norms = (float*)(ws + 16 * MB);              // 256 KB
  int*    sel   = (int*)(ws + 16 * MB + (256u << 10)); // 57 KB
  float*  Ol    = (float*)(ws + 16 * MB + (320u << 10)); // 229 KB
  float*  Oo    = (float*)(ws + 17 * MB);              // 14.7 MB
  bf16_t* AOhi = Qhi;
  bf16_t* Khi = (bf16_t*)d_out;

  dim3 blk(256);
  gemm_q<<<dim3(8, 32), blk, 0, stream>>>(x, Wq, bq, Qhi, norms);
  gemm_kv<<<dim3(8, 32, 2), blk, 0, stream>>>(x, Wk, Wv, bk, bv, Khi, VThi);
  topk_kernel<<<dim3(32), dim3(1024), 0, stream>>>(norms, sel);
  attn_kernel<<<dim3(32 * 7 * KSPLIT), blk, 0, stream>>>(Qhi, Khi, VThi, sel, Ol, Oo);
  meanfill_kernel<<<dim3(32, 8), blk, 0, stream>>>(VThi, AOhi);
  combine_kernel<<<dim3(32, 28), blk, 0, stream>>>(Ol, Oo, sel, AOhi);
  gemm_out<<<dim3(8, 32), blk, 0, stream>>>(AOhi, Wo, bo, out);
}

// Round 6
// 311.080 us; speedup vs baseline: 1.8564x; 1.1039x over previous
//
#include <hip/hip_runtime.h>
#include <hip/hip_bf16.h>
#include <math.h>

typedef __bf16 bf16_t;
typedef __bf16 bf16x8 __attribute__((ext_vector_type(8)));
typedef __bf16 bf16x4 __attribute__((ext_vector_type(4)));
typedef float  f32x4  __attribute__((ext_vector_type(4)));

#define L_DIM 2048
#define D_DIM 1024
#define H_DIM 16
#define M_DIM 4096
#define KTOP 409
#define SLOTS 448    // 7 * 64, padded (sel = -1 beyond KTOP)
#define KSPLIT 4
#define KCHUNK 512   // L_DIM / KSPLIT

// split f32 into bf16 hi + bf16 lo (a ~= hi + lo)
__device__ __forceinline__ void split2(float a, bf16_t& h, bf16_t& l) {
  h = (bf16_t)a;
  l = (bf16_t)(a - (float)h);
}

// async global -> LDS, 16B per lane (lane i lands at ldsbase + i*16)
__device__ __forceinline__ void gld16(const bf16_t* g, bf16_t* l) {
  __builtin_amdgcn_global_load_lds(
      (const __attribute__((address_space(1))) void*)g,
      (__attribute__((address_space(3))) void*)l, 16, 0, 0);
}

// stage a 128x32 bf16 tile (src row stride D_DIM) into unpadded LDS tile.
// wave w covers segments {2w, 2w+1}; seg s = rows 16s..16s+15.
#define STAGE_TILE(src, dst)                                                  \
  {                                                                           \
    const int seg0 = wave * 2;                                                \
    const int r0 = seg0 * 16 + (lane >> 2);                                   \
    const int c0 = (lane & 3) * 8;                                            \
    gld16((src) + (size_t)r0 * D_DIM + c0, (dst) + seg0 * 512);               \
    gld16((src) + (size_t)(r0 + 16) * D_DIM + c0, (dst) + (seg0 + 1) * 512);  \
  }

// ---------------------------------------------------------------------------
// prep: pre-split x and Wq into bf16 hi/lo; pre-round Wk/Wv/Wo to bf16.
// xhi doubles as the single-bf16 x for the K/V projections.
// ---------------------------------------------------------------------------
__global__ __launch_bounds__(256) void prep_kernel(
    const float* __restrict__ x,  const float* __restrict__ Wq,
    const float* __restrict__ Wk, const float* __restrict__ Wv,
    const float* __restrict__ Wo,
    bf16_t* __restrict__ xhi, bf16_t* __restrict__ xlo,
    bf16_t* __restrict__ Wqhi, bf16_t* __restrict__ Wqlo,
    bf16_t* __restrict__ Wkb,  bf16_t* __restrict__ Wvb,
    bf16_t* __restrict__ Wob)
{
  const int XV = (M_DIM * D_DIM) / 4;   // 1048576 f32x4 slots
  const int WV = (D_DIM * D_DIM) / 4;   // 262144
  int i = blockIdx.x * 256 + threadIdx.x;
  if (i < XV) {
    f32x4 v = ((const f32x4*)x)[i];
    bf16x4 h, l;
    #pragma unroll
    for (int j = 0; j < 4; ++j) { bf16_t hh, ll; split2(v[j], hh, ll); h[j] = hh; l[j] = ll; }
    ((bf16x4*)xhi)[i] = h;
    ((bf16x4*)xlo)[i] = l;
  } else if (i < XV + WV) {
    int j0 = i - XV;
    f32x4 v = ((const f32x4*)Wq)[j0];
    bf16x4 h, l;
    #pragma unroll
    for (int j = 0; j < 4; ++j) { bf16_t hh, ll; split2(v[j], hh, ll); h[j] = hh; l[j] = ll; }
    ((bf16x4*)Wqhi)[j0] = h;
    ((bf16x4*)Wqlo)[j0] = l;
  } else if (i < XV + 2 * WV) {
    int j0 = i - XV - WV;
    f32x4 v = ((const f32x4*)Wk)[j0];
    bf16x4 h;
    #pragma unroll
    for (int j = 0; j < 4; ++j) h[j] = (bf16_t)v[j];
    ((bf16x4*)Wkb)[j0] = h;
  } else if (i < XV + 3 * WV) {
    int j0 = i - XV - 2 * WV;
    f32x4 v = ((const f32x4*)Wv)[j0];
    bf16x4 h;
    #pragma unroll
    for (int j = 0; j < 4; ++j) h[j] = (bf16_t)v[j];
    ((bf16x4*)Wvb)[j0] = h;
  } else {
    int j0 = i - XV - 3 * WV;
    f32x4 v = ((const f32x4*)Wo)[j0];
    bf16x4 h;
    #pragma unroll
    for (int j = 0; j < 4; ++j) h[j] = (bf16_t)v[j];
    ((bf16x4*)Wob)[j0] = h;
  }
}

// ---------------------------------------------------------------------------
// Fused QKV projections, async global_load_lds staging (m97 structure).
// z=0: Q = split-bf16 3-product (feeds f32 norms); z=1: K; z=2: V transposed.
// Grid 8x32x3 = 768 blocks -> 3 blocks/CU co-residency.
// ---------------------------------------------------------------------------
__global__ __launch_bounds__(256) void gemm_qkv(
    const bf16_t* __restrict__ xhi, const bf16_t* __restrict__ xlo,
    const bf16_t* __restrict__ Wqhi, const bf16_t* __restrict__ Wqlo,
    const bf16_t* __restrict__ Wkb, const bf16_t* __restrict__ Wvb,
    const float* __restrict__ bq, const float* __restrict__ bk, const float* __restrict__ bv,
    bf16_t* __restrict__ Qhi, bf16_t* __restrict__ Khi, bf16_t* __restrict__ VThi,
    float* __restrict__ norms)
{
  const int z = blockIdx.z;
  const int n0   = blockIdx.x * 128;
  const int row0 = blockIdx.y * 128;

  // 4 unpadded 128x32 bf16 tiles (8 KB each): [0]=Ahi [1]=Alo [2]=Bhi [3]=Blo
  __shared__ __align__(16) bf16_t sm[4][4096];

  const int tid  = threadIdx.x;
  const int lane = tid & 63;
  const int wave = tid >> 6;
  const int wr = wave >> 1, wc = wave & 1;
  const int lm = lane & 15, quad = lane >> 4;

  const f32x4 vzero = {0.f, 0.f, 0.f, 0.f};
  f32x4 acc[4][4];
  #pragma unroll
  for (int mi = 0; mi < 4; ++mi)
    #pragma unroll
    for (int ni = 0; ni < 4; ++ni) acc[mi][ni] = vzero;

  if (z == 0) {
    for (int k0 = 0; k0 < D_DIM; k0 += 32) {
      __syncthreads();
      STAGE_TILE(xhi  + (size_t)row0 * D_DIM + k0, sm[0]);
      STAGE_TILE(xlo  + (size_t)row0 * D_DIM + k0, sm[1]);
      STAGE_TILE(Wqhi + (size_t)n0   * D_DIM + k0, sm[2]);
      STAGE_TILE(Wqlo + (size_t)n0   * D_DIM + k0, sm[3]);
      __syncthreads();
      bf16x8 afh[4], afl[4], bfh[4], bfl[4];
      #pragma unroll
      for (int mi = 0; mi < 4; ++mi) {
        afh[mi] = *reinterpret_cast<const bf16x8*>(&sm[0][(wr * 64 + mi * 16 + lm) * 32 + quad * 8]);
        afl[mi] = *reinterpret_cast<const bf16x8*>(&sm[1][(wr * 64 + mi * 16 + lm) * 32 + quad * 8]);
      }
      #pragma unroll
      for (int ni = 0; ni < 4; ++ni) {
        bfh[ni] = *reinterpret_cast<const bf16x8*>(&sm[2][(wc * 64 + ni * 16 + lm) * 32 + quad * 8]);
        bfl[ni] = *reinterpret_cast<const bf16x8*>(&sm[3][(wc * 64 + ni * 16 + lm) * 32 + quad * 8]);
      }
      #pragma unroll
      for (int mi = 0; mi < 4; ++mi)
        #pragma unroll
        for (int ni = 0; ni < 4; ++ni) {
          acc[mi][ni] = __builtin_amdgcn_mfma_f32_16x16x32_bf16(afh[mi], bfh[ni], acc[mi][ni], 0, 0, 0);
          acc[mi][ni] = __builtin_amdgcn_mfma_f32_16x16x32_bf16(afh[mi], bfl[ni], acc[mi][ni], 0, 0, 0);
          acc[mi][ni] = __builtin_amdgcn_mfma_f32_16x16x32_bf16(afl[mi], bfh[ni], acc[mi][ni], 0, 0, 0);
        }
    }

    float bvv[4];
    #pragma unroll
    for (int ni = 0; ni < 4; ++ni) bvv[ni] = bq[n0 + wc * 64 + ni * 16 + lm];
    #pragma unroll
    for (int mi = 0; mi < 4; ++mi)
      #pragma unroll
      for (int ni = 0; ni < 4; ++ni)
        #pragma unroll
        for (int r = 0; r < 4; ++r) acc[mi][ni][r] += bvv[ni];

    // f32 row-norms per head (wave spans one head's 64 cols)
    const int h = (n0 + wc * 64) >> 6;
    #pragma unroll
    for (int mi = 0; mi < 4; ++mi)
      #pragma unroll
      for (int r = 0; r < 4; ++r) {
        float s = 0.f;
        #pragma unroll
        for (int ni = 0; ni < 4; ++ni) { float v = acc[mi][ni][r]; s += v * v; }
        s += __shfl_xor(s, 1); s += __shfl_xor(s, 2);
        s += __shfl_xor(s, 4); s += __shfl_xor(s, 8);
        if (lm == 0) {
          int row = row0 + wr * 64 + mi * 16 + quad * 4 + r;
          int bb = row >> 11, ll = row & (L_DIM - 1);
          norms[(bb * H_DIM + h) * L_DIM + ll] = s;
        }
      }

    #pragma unroll
    for (int mi = 0; mi < 4; ++mi)
      #pragma unroll
      for (int r = 0; r < 4; ++r) {
        int row = row0 + wr * 64 + mi * 16 + quad * 4 + r;
        #pragma unroll
        for (int ni = 0; ni < 4; ++ni)
          Qhi[(size_t)row * D_DIM + n0 + wc * 64 + ni * 16 + lm] = (bf16_t)acc[mi][ni][r];
      }
  } else {
    const bf16_t* W = (z == 1) ? Wkb : Wvb;
    for (int k0 = 0; k0 < D_DIM; k0 += 32) {
      __syncthreads();
      STAGE_TILE(xhi + (size_t)row0 * D_DIM + k0, sm[0]);
      STAGE_TILE(W   + (size_t)n0   * D_DIM + k0, sm[2]);
      __syncthreads();
      bf16x8 af[4], bfr[4];
      #pragma unroll
      for (int mi = 0; mi < 4; ++mi)
        af[mi] = *reinterpret_cast<const bf16x8*>(&sm[0][(wr * 64 + mi * 16 + lm) * 32 + quad * 8]);
      #pragma unroll
      for (int ni = 0; ni < 4; ++ni)
        bfr[ni] = *reinterpret_cast<const bf16x8*>(&sm[2][(wc * 64 + ni * 16 + lm) * 32 + quad * 8]);
      #pragma unroll
      for (int mi = 0; mi < 4; ++mi)
        #pragma unroll
        for (int ni = 0; ni < 4; ++ni)
          acc[mi][ni] = __builtin_amdgcn_mfma_f32_16x16x32_bf16(af[mi], bfr[ni], acc[mi][ni], 0, 0, 0);
    }

    const float* bias = (z == 1) ? bk : bv;
    float bvv[4];
    #pragma unroll
    for (int ni = 0; ni < 4; ++ni) bvv[ni] = bias[n0 + wc * 64 + ni * 16 + lm];
    #pragma unroll
    for (int mi = 0; mi < 4; ++mi)
      #pragma unroll
      for (int ni = 0; ni < 4; ++ni)
        #pragma unroll
        for (int r = 0; r < 4; ++r) acc[mi][ni][r] += bvv[ni];

    if (z == 1) {
      #pragma unroll
      for (int mi = 0; mi < 4; ++mi)
        #pragma unroll
        for (int r = 0; r < 4; ++r) {
          int row = row0 + wr * 64 + mi * 16 + quad * 4 + r;
          #pragma unroll
          for (int ni = 0; ni < 4; ++ni)
            Khi[(size_t)row * D_DIM + n0 + wc * 64 + ni * 16 + lm] = (bf16_t)acc[mi][ni][r];
        }
    } else {
      // VT[(b*1024 + col) * 2048 + l]
      #pragma unroll
      for (int mi = 0; mi < 4; ++mi) {
        int rbase = row0 + wr * 64 + mi * 16 + quad * 4;
        int bb = rbase >> 11, l0 = rbase & (L_DIM - 1);
        #pragma unroll
        for (int ni = 0; ni < 4; ++ni) {
          int col = n0 + wc * 64 + ni * 16 + lm;
          bf16x4 wv;
          #pragma unroll
          for (int r = 0; r < 4; ++r) wv[r] = (bf16_t)acc[mi][ni][r];
          *reinterpret_cast<bf16x4*>(&VThi[((size_t)(bb * D_DIM + col)) * L_DIM + l0]) = wv;
        }
      }
    }
  }
}

// ---------------------------------------------------------------------------
// Output projection: AO bf16 x Wob bf16, async staging -> f32 out.
// ---------------------------------------------------------------------------
__global__ __launch_bounds__(256) void gemm_out(
    const bf16_t* __restrict__ Ahi, const bf16_t* __restrict__ Wob,
    const float* __restrict__ bias, float* __restrict__ C)
{
  const int n0   = blockIdx.x * 128;
  const int row0 = blockIdx.y * 128;

  __shared__ __align__(16) bf16_t sm[2][4096];

  const int tid  = threadIdx.x;
  const int lane = tid & 63;
  const int wave = tid >> 6;
  const int wr = wave >> 1, wc = wave & 1;
  const int lm = lane & 15, quad = lane >> 4;

  const f32x4 vzero = {0.f, 0.f, 0.f, 0.f};
  f32x4 acc[4][4];
  #pragma unroll
  for (int mi = 0; mi < 4; ++mi)
    #pragma unroll
    for (int ni = 0; ni < 4; ++ni) acc[mi][ni] = vzero;

  for (int k0 = 0; k0 < D_DIM; k0 += 32) {
    __syncthreads();
    STAGE_TILE(Ahi + (size_t)row0 * D_DIM + k0, sm[0]);
    STAGE_TILE(Wob + (size_t)n0   * D_DIM + k0, sm[1]);
    __syncthreads();
    bf16x8 af[4], bfr[4];
    #pragma unroll
    for (int mi = 0; mi < 4; ++mi)
      af[mi] = *reinterpret_cast<const bf16x8*>(&sm[0][(wr * 64 + mi * 16 + lm) * 32 + quad * 8]);
    #pragma unroll
    for (int ni = 0; ni < 4; ++ni)
      bfr[ni] = *reinterpret_cast<const bf16x8*>(&sm[1][(wc * 64 + ni * 16 + lm) * 32 + quad * 8]);
    #pragma unroll
    for (int mi = 0; mi < 4; ++mi)
      #pragma unroll
      for (int ni = 0; ni < 4; ++ni)
        acc[mi][ni] = __builtin_amdgcn_mfma_f32_16x16x32_bf16(af[mi], bfr[ni], acc[mi][ni], 0, 0, 0);
  }

  float bvv[4];
  #pragma unroll
  for (int ni = 0; ni < 4; ++ni) bvv[ni] = bias[n0 + wc * 64 + ni * 16 + lm];
  #pragma unroll
  for (int mi = 0; mi < 4; ++mi)
    #pragma unroll
    for (int r = 0; r < 4; ++r) {
      int row = row0 + wr * 64 + mi * 16 + quad * 4 + r;
      #pragma unroll
      for (int ni = 0; ni < 4; ++ni)
        C[(size_t)row * D_DIM + n0 + wc * 64 + ni * 16 + lm] = acc[mi][ni][r] + bvv[ni];
    }
}

// ---------------------------------------------------------------------------
// Exact top-409 per (b,h): bitonic sort (norm desc, idx asc) = lax.top_k order.
// ---------------------------------------------------------------------------
__global__ __launch_bounds__(1024) void topk_kernel(
    const float* __restrict__ norms, int* __restrict__ sel)
{
  const int bh = blockIdx.x;
  __shared__ __align__(16) float val[L_DIM];
  __shared__ __align__(16) int   idx[L_DIM];
  const int t = threadIdx.x;
  for (int i = t; i < L_DIM; i += 1024) {
    val[i] = norms[bh * L_DIM + i];
    idx[i] = i;
  }
  __syncthreads();
  for (int k = 2; k <= L_DIM; k <<= 1) {
    for (int j = k >> 1; j > 0; j >>= 1) {
      for (int i = t; i < L_DIM; i += 1024) {
        int ixj = i ^ j;
        if (ixj > i) {
          float v1 = val[i], v2 = val[ixj];
          int   i1 = idx[i], i2 = idx[ixj];
          bool up = ((i & k) == 0);
          bool sw = up ? ((v2 > v1) || (v2 == v1 && i2 < i1))
                       : ((v1 > v2) || (v1 == v2 && i1 < i2));
          if (sw) { val[i] = v2; val[ixj] = v1; idx[i] = i2; idx[ixj] = i1; }
        }
      }
      __syncthreads();
    }
  }
  for (int i = t; i < SLOTS; i += 1024)
    sel[bh * SLOTS + i] = (i < KTOP) ? idx[i] : -1;
}

// ---------------------------------------------------------------------------
// K-split flash attention, single-bf16 Q/K/V. Block = 4 waves x 16 q-slots;
// keys [ks*512, +512). No softmax max (scores bounded); l reduced post-loop.
// ---------------------------------------------------------------------------
__global__ __launch_bounds__(256) void attn_kernel(
    const bf16_t* __restrict__ Qhi,
    const bf16_t* __restrict__ Khi,
    const bf16_t* __restrict__ VThi,
    const int* __restrict__ sel,
    float* __restrict__ Ol, float* __restrict__ Oo)
{
  const int bx = blockIdx.x;
  const int bh = bx & 31;
  const int t2 = bx >> 5;
  const int qc = t2 % 7;
  const int ks = t2 / 7;
  const int b = bh >> 4, h = bh & 15;
  const int wave = threadIdx.x >> 6;
  const int lane = threadIdx.x & 63;
  const int lm = lane & 15, quad = lane >> 4;

  __shared__ __align__(16) bf16_t sPh[4][16][40];

  const int qbase = qc * 64 + wave * 16;
  const int qi = sel[bh * SLOTS + qbase + lm];
  const size_t qo = ((size_t)(b * L_DIM + (qi >= 0 ? qi : 0))) * D_DIM + h * 64;
  const bf16x8 qa0 = *reinterpret_cast<const bf16x8*>(&Qhi[qo + quad * 8]);
  const bf16x8 qa1 = *reinterpret_cast<const bf16x8*>(&Qhi[qo + 32 + quad * 8]);

  const f32x4 vzero = {0.f, 0.f, 0.f, 0.f};
  float l_l[4] = {0.f, 0.f, 0.f, 0.f};
  f32x4 o[4];
  #pragma unroll
  for (int ni = 0; ni < 4; ++ni) o[ni] = vzero;

  const float scale = 0.125f;
  const size_t kbase = (size_t)(b * L_DIM) * D_DIM + h * 64;
  const int key0 = ks * KCHUNK;

  for (int kt = 0; kt < KCHUNK; kt += 32) {
    f32x4 s0 = vzero, s1 = vzero;
    {
      size_t kr0 = kbase + (size_t)(key0 + kt + lm) * D_DIM;
      bf16x8 kb0 = *reinterpret_cast<const bf16x8*>(&Khi[kr0 + quad * 8]);
      bf16x8 kb1 = *reinterpret_cast<const bf16x8*>(&Khi[kr0 + 32 + quad * 8]);
      s0 = __builtin_amdgcn_mfma_f32_16x16x32_bf16(qa0, kb0, s0, 0, 0, 0);
      s0 = __builtin_amdgcn_mfma_f32_16x16x32_bf16(qa1, kb1, s0, 0, 0, 0);
      size_t kr1 = kbase + (size_t)(key0 + kt + 16 + lm) * D_DIM;
      bf16x8 kb2 = *reinterpret_cast<const bf16x8*>(&Khi[kr1 + quad * 8]);
      bf16x8 kb3 = *reinterpret_cast<const bf16x8*>(&Khi[kr1 + 32 + quad * 8]);
      s1 = __builtin_amdgcn_mfma_f32_16x16x32_bf16(qa0, kb2, s1, 0, 0, 0);
      s1 = __builtin_amdgcn_mfma_f32_16x16x32_bf16(qa1, kb3, s1, 0, 0, 0);
    }
    #pragma unroll
    for (int r = 0; r < 4; ++r) {
      float p0 = __expf(s0[r] * scale);
      float p1 = __expf(s1[r] * scale);
      l_l[r] += p0 + p1;
      sPh[wave][quad * 4 + r][lm]      = (bf16_t)p0;
      sPh[wave][quad * 4 + r][16 + lm] = (bf16_t)p1;
    }
    __syncthreads();
    bf16x8 pah = *reinterpret_cast<const bf16x8*>(&sPh[wave][lm][quad * 8]);
    #pragma unroll
    for (int ni = 0; ni < 4; ++ni) {
      size_t vo = ((size_t)(b * D_DIM + h * 64 + ni * 16 + lm)) * L_DIM + key0 + kt + quad * 8;
      const bf16x8 vbh = *reinterpret_cast<const bf16x8*>(&VThi[vo]);
      o[ni] = __builtin_amdgcn_mfma_f32_16x16x32_bf16(pah, vbh, o[ni], 0, 0, 0);
    }
    __syncthreads();
  }

  #pragma unroll
  for (int r = 0; r < 4; ++r) {
    l_l[r] += __shfl_xor(l_l[r], 1);
    l_l[r] += __shfl_xor(l_l[r], 2);
    l_l[r] += __shfl_xor(l_l[r], 4);
    l_l[r] += __shfl_xor(l_l[r], 8);
  }

  #pragma unroll
  for (int r = 0; r < 4; ++r) {
    int slot = qbase + quad * 4 + r;
    int s2 = sel[bh * SLOTS + slot];
    if (s2 >= 0) {
      size_t gs = (size_t)(bh * SLOTS + slot) * KSPLIT + ks;
      if (lm == 0) Ol[gs] = l_l[r];
      #pragma unroll
      for (int ni = 0; ni < 4; ++ni)
        Oo[gs * 64 + ni * 16 + lm] = o[ni][r];
    }
  }
}

// ---------------------------------------------------------------------------
// Combine ksplit partials -> AO (selected rows; meanfill covered the rest).
// ---------------------------------------------------------------------------
__global__ __launch_bounds__(256) void combine_kernel(
    const float* __restrict__ Ol, const float* __restrict__ Oo,
    const int* __restrict__ sel, bf16_t* __restrict__ AOhi)
{
  const int bh = blockIdx.x;
  const int b = bh >> 4, h = bh & 15;
  const int chunk = blockIdx.y;
  const int tid = threadIdx.x;
  const int dim = tid & 63;
  const int sl  = tid >> 6;
  #pragma unroll
  for (int p = 0; p < 4; ++p) {
    int slot = chunk * 16 + p * 4 + sl;
    int qi = sel[bh * SLOTS + slot];
    if (qi < 0) continue;
    size_t gs = (size_t)(bh * SLOTS + slot) * KSPLIT;
    float L = Ol[gs] + Ol[gs + 1] + Ol[gs + 2] + Ol[gs + 3];
    float ov = Oo[gs * 64 + dim] + Oo[(gs + 1) * 64 + dim]
             + Oo[(gs + 2) * 64 + dim] + Oo[(gs + 3) * 64 + dim];
    AOhi[((size_t)(b * L_DIM + qi)) * D_DIM + h * 64 + dim] = (bf16_t)(ov / L);
  }
}

// ---------------------------------------------------------------------------
// mean(V) to EVERY AO row; combine overwrites selected rows.
// ---------------------------------------------------------------------------
__global__ __launch_bounds__(256) void meanfill_kernel(
    const bf16_t* __restrict__ VThi, bf16_t* __restrict__ AOhi)
{
  const int bh = blockIdx.x;
  const int b = bh >> 4, h = bh & 15;
  const int t = threadIdx.x;
  __shared__ __align__(16) bf16_t smh[64];
  {
    const int hd = t >> 2, part = t & 3;
    size_t base = ((size_t)(b * D_DIM + h * 64 + hd)) * L_DIM;
    float s = 0.f;
    for (int l0 = part * 512; l0 < part * 512 + 512; l0 += 8) {
      bf16x8 vh = *reinterpret_cast<const bf16x8*>(&VThi[base + l0]);
      #pragma unroll
      for (int j = 0; j < 8; ++j) s += (float)vh[j];
    }
    s += __shfl_xor(s, 1);
    s += __shfl_xor(s, 2);
    if (part == 0) smh[hd] = (bf16_t)(s * (1.0f / (float)L_DIM));
  }
  __syncthreads();
  const int lbase = blockIdx.y * 256;
  for (int i = t; i < 256 * 64; i += 256) {
    int l = lbase + (i >> 6), hd = i & 63;
    AOhi[((size_t)(b * L_DIM + l)) * D_DIM + h * 64 + hd] = smh[hd];
  }
}

// ---------------------------------------------------------------------------
extern "C" void kernel_launch(void* const* d_in, const int* in_sizes, int n_in,
                              void* d_out, int out_size, void* d_ws, size_t ws_size,
                              hipStream_t stream) {
  const float* x  = (const float*)d_in[0];
  const float* Wq = (const float*)d_in[1];
  const float* bq = (const float*)d_in[2];
  const float* Wk = (const float*)d_in[3];
  const float* bk = (const float*)d_in[4];
  const float* Wv = (const float*)d_in[5];
  const float* bv = (const float*)d_in[6];
  const float* Wo = (const float*)d_in[7];
  const float* bo = (const float*)d_in[8];
  float* out = (float*)d_out;

  // ws layout (~42.6 MB):
  //  [0,8)    Qhi  (aliased as AOhi after attn)
  //  [8,16)   VThi
  //  [16,24)  xhi  -+ dead after gemm_qkv; region [16,32) reused for Oo
  //  [24,32)  xlo  -+
  //  [32,34)  Wqhi  [34,36) Wqlo  [36,38) Wkb  [38,40) Wvb  [40,42) Wob
  //  [42,42.25) norms   then sel (57 KB), Ol (229 KB)
  // Khi lives in d_out (8 of 16 MB) — dead until gemm_out rewrites d_out.
  const size_t MB = 1u << 20;
  char* ws = (char*)d_ws;
  bf16_t* Qhi  = (bf16_t*)(ws);
  bf16_t* VThi = (bf16_t*)(ws + 8 * MB);
  bf16_t* xhi  = (bf16_t*)(ws + 16 * MB);
  bf16_t* xlo  = (bf16_t*)(ws + 24 * MB);
  float*  Oo   = (float*)(ws + 16 * MB);          // aliases xhi/xlo (14.7 MB)
  bf16_t* Wqhi = (bf16_t*)(ws + 32 * MB);
  bf16_t* Wqlo = (bf16_t*)(ws + 34 * MB);
  bf16_t* Wkb  = (bf16_t*)(ws + 36 * MB);
  bf16_t* Wvb  = (bf16_t*)(ws + 38 * MB);
  bf16_t* Wob  = (bf16_t*)(ws + 40 * MB);
  float*  norms = (float*)(ws + 42 * MB);
  int*    sel   = (int*)(ws + 42 * MB + (256u << 10));
  float*  Ol    = (float*)(ws + 42 * MB + (320u << 10));
  bf16_t* AOhi = Qhi;
  bf16_t* Khi = (bf16_t*)d_out;

  dim3 blk(256);
  prep_kernel<<<dim3(8192), blk, 0, stream>>>(x, Wq, Wk, Wv, Wo,
                                              xhi, xlo, Wqhi, Wqlo, Wkb, Wvb, Wob);
  gemm_qkv<<<dim3(8, 32, 3), blk, 0, stream>>>(xhi, xlo, Wqhi, Wqlo, Wkb, Wvb,
                                               bq, bk, bv, Qhi, Khi, VThi, norms);
  topk_kernel<<<dim3(32), dim3(1024), 0, stream>>>(norms, sel);
  attn_kernel<<<dim3(32 * 7 * KSPLIT), blk, 0, stream>>>(Qhi, Khi, VThi, sel, Ol, Oo);
  meanfill_kernel<<<dim3(32, 8), blk, 0, stream>>>(VThi, AOhi);
  combine_kernel<<<dim3(32, 28), blk, 0, stream>>>(Ol, Oo, sel, AOhi);
  gemm_out<<<dim3(8, 32), blk, 0, stream>>>(AOhi, Wob, bo, out);
}

// Round 7
// 308.523 us; speedup vs baseline: 1.8718x; 1.0083x over previous
//
#include <hip/hip_runtime.h>
#include <hip/hip_bf16.h>
#include <math.h>

typedef __bf16 bf16_t;
typedef __bf16 bf16x8 __attribute__((ext_vector_type(8)));
typedef __bf16 bf16x4 __attribute__((ext_vector_type(4)));
typedef float  f32x4  __attribute__((ext_vector_type(4)));

#define L_DIM 2048
#define D_DIM 1024
#define H_DIM 16
#define M_DIM 4096
#define KTOP 409
#define SLOTS 448    // 7 * 64, padded (sel = -1 beyond KTOP)
#define KSPLIT 4
#define KCHUNK 512   // L_DIM / KSPLIT

// split f32 into bf16 hi + bf16 lo (a ~= hi + lo)
__device__ __forceinline__ void split2(float a, bf16_t& h, bf16_t& l) {
  h = (bf16_t)a;
  l = (bf16_t)(a - (float)h);
}

// async global -> LDS, 16B per lane; lds ptr must be wave-uniform (m104/m108)
__device__ __forceinline__ void gld16(const bf16_t* g, bf16_t* l) {
  __builtin_amdgcn_global_load_lds(
      (const __attribute__((address_space(1))) void*)g,
      (__attribute__((address_space(3))) void*)l, 16, 0, 0);
}

// stage a 128x32 bf16 tile (row stride D_DIM) into unpadded LDS.
// wave w covers segments {2w, 2w+1}; seg s = rows 16s..16s+15.
#define STAGE_TILE128(src, dst)                                               \
  {                                                                           \
    const int seg0 = wave * 2;                                                \
    const int r0 = seg0 * 16 + (lane >> 2);                                   \
    const int c0 = (lane & 3) * 8;                                            \
    gld16((src) + (size_t)r0 * D_DIM + c0, (dst) + seg0 * 512);               \
    gld16((src) + (size_t)(r0 + 16) * D_DIM + c0, (dst) + (seg0 + 1) * 512);  \
  }

// stage a 64x32 bf16 tile: one 16-row segment per wave, one gld16 per thread.
#define STAGE_TILE64(src, dst)                                                \
  {                                                                           \
    const int r0 = wave * 16 + (lane >> 2);                                   \
    const int c0 = (lane & 3) * 8;                                            \
    gld16((src) + (size_t)r0 * D_DIM + c0, (dst) + wave * 512);               \
  }

// ---------------------------------------------------------------------------
// prep: pre-split x and Wq into bf16 hi/lo; pre-round Wk/Wv/Wo to bf16.
// ---------------------------------------------------------------------------
__global__ __launch_bounds__(256) void prep_kernel(
    const float* __restrict__ x,  const float* __restrict__ Wq,
    const float* __restrict__ Wk, const float* __restrict__ Wv,
    const float* __restrict__ Wo,
    bf16_t* __restrict__ xhi, bf16_t* __restrict__ xlo,
    bf16_t* __restrict__ Wqhi, bf16_t* __restrict__ Wqlo,
    bf16_t* __restrict__ Wkb,  bf16_t* __restrict__ Wvb,
    bf16_t* __restrict__ Wob)
{
  const int XV = (M_DIM * D_DIM) / 4;
  const int WV = (D_DIM * D_DIM) / 4;
  int i = blockIdx.x * 256 + threadIdx.x;
  if (i < XV) {
    f32x4 v = ((const f32x4*)x)[i];
    bf16x4 h, l;
    #pragma unroll
    for (int j = 0; j < 4; ++j) { bf16_t hh, ll; split2(v[j], hh, ll); h[j] = hh; l[j] = ll; }
    ((bf16x4*)xhi)[i] = h;
    ((bf16x4*)xlo)[i] = l;
  } else if (i < XV + WV) {
    int j0 = i - XV;
    f32x4 v = ((const f32x4*)Wq)[j0];
    bf16x4 h, l;
    #pragma unroll
    for (int j = 0; j < 4; ++j) { bf16_t hh, ll; split2(v[j], hh, ll); h[j] = hh; l[j] = ll; }
    ((bf16x4*)Wqhi)[j0] = h;
    ((bf16x4*)Wqlo)[j0] = l;
  } else if (i < XV + 2 * WV) {
    int j0 = i - XV - WV;
    f32x4 v = ((const f32x4*)Wk)[j0];
    bf16x4 h;
    #pragma unroll
    for (int j = 0; j < 4; ++j) h[j] = (bf16_t)v[j];
    ((bf16x4*)Wkb)[j0] = h;
  } else if (i < XV + 3 * WV) {
    int j0 = i - XV - 2 * WV;
    f32x4 v = ((const f32x4*)Wv)[j0];
    bf16x4 h;
    #pragma unroll
    for (int j = 0; j < 4; ++j) h[j] = (bf16_t)v[j];
    ((bf16x4*)Wvb)[j0] = h;
  } else {
    int j0 = i - XV - 3 * WV;
    f32x4 v = ((const f32x4*)Wo)[j0];
    bf16x4 h;
    #pragma unroll
    for (int j = 0; j < 4; ++j) h[j] = (bf16_t)v[j];
    ((bf16x4*)Wob)[j0] = h;
  }
}

// ---------------------------------------------------------------------------
// Fused QKV projections, async staging, balanced grid (8,32,4) = 4 blocks/CU.
// z=0/1: Q M-halves in 64-row tiles (split-bf16 3-product + f32 norms);
// z=2: K 128-tiles; z=3: V 128-tiles, transposed store.
// ---------------------------------------------------------------------------
__global__ __launch_bounds__(256) void gemm_qkv(
    const bf16_t* __restrict__ xhi, const bf16_t* __restrict__ xlo,
    const bf16_t* __restrict__ Wqhi, const bf16_t* __restrict__ Wqlo,
    const bf16_t* __restrict__ Wkb, const bf16_t* __restrict__ Wvb,
    const float* __restrict__ bq, const float* __restrict__ bk, const float* __restrict__ bv,
    bf16_t* __restrict__ Qhi, bf16_t* __restrict__ Khi, bf16_t* __restrict__ VThi,
    float* __restrict__ norms)
{
  const int z = blockIdx.z;
  const int n0 = blockIdx.x * 128;

  __shared__ __align__(16) bf16_t sm[12288];   // 24 KB, carved per z

  const int tid  = threadIdx.x;
  const int lane = tid & 63;
  const int wave = tid >> 6;
  const int lm = lane & 15, quad = lane >> 4;

  const f32x4 vzero = {0.f, 0.f, 0.f, 0.f};

  if (z <= 1) {
    // ---- Q path: 64 rows x 128 cols, 3-product split-bf16 ----
    const int row0 = z * 2048 + blockIdx.y * 64;
    bf16_t* sAhi = sm;            // 64x32 = 2048
    bf16_t* sAlo = sm + 2048;     // 2048
    bf16_t* sBhi = sm + 4096;     // 128x32 = 4096
    bf16_t* sBlo = sm + 8192;     // 4096
    const int wr = wave >> 1, wc = wave & 1;   // wave tile: 32 rows x 64 cols

    f32x4 acc[2][4];
    #pragma unroll
    for (int mi = 0; mi < 2; ++mi)
      #pragma unroll
      for (int ni = 0; ni < 4; ++ni) acc[mi][ni] = vzero;

    for (int k0 = 0; k0 < D_DIM; k0 += 32) {
      __syncthreads();
      STAGE_TILE64(xhi + (size_t)row0 * D_DIM + k0, sAhi);
      STAGE_TILE64(xlo + (size_t)row0 * D_DIM + k0, sAlo);
      STAGE_TILE128(Wqhi + (size_t)n0 * D_DIM + k0, sBhi);
      STAGE_TILE128(Wqlo + (size_t)n0 * D_DIM + k0, sBlo);
      __syncthreads();
      bf16x8 afh[2], afl[2], bfh[4], bfl[4];
      #pragma unroll
      for (int mi = 0; mi < 2; ++mi) {
        afh[mi] = *reinterpret_cast<const bf16x8*>(&sAhi[(wr * 32 + mi * 16 + lm) * 32 + quad * 8]);
        afl[mi] = *reinterpret_cast<const bf16x8*>(&sAlo[(wr * 32 + mi * 16 + lm) * 32 + quad * 8]);
      }
      #pragma unroll
      for (int ni = 0; ni < 4; ++ni) {
        bfh[ni] = *reinterpret_cast<const bf16x8*>(&sBhi[(wc * 64 + ni * 16 + lm) * 32 + quad * 8]);
        bfl[ni] = *reinterpret_cast<const bf16x8*>(&sBlo[(wc * 64 + ni * 16 + lm) * 32 + quad * 8]);
      }
      #pragma unroll
      for (int mi = 0; mi < 2; ++mi)
        #pragma unroll
        for (int ni = 0; ni < 4; ++ni) {
          acc[mi][ni] = __builtin_amdgcn_mfma_f32_16x16x32_bf16(afh[mi], bfh[ni], acc[mi][ni], 0, 0, 0);
          acc[mi][ni] = __builtin_amdgcn_mfma_f32_16x16x32_bf16(afh[mi], bfl[ni], acc[mi][ni], 0, 0, 0);
          acc[mi][ni] = __builtin_amdgcn_mfma_f32_16x16x32_bf16(afl[mi], bfh[ni], acc[mi][ni], 0, 0, 0);
        }
    }

    float bvv[4];
    #pragma unroll
    for (int ni = 0; ni < 4; ++ni) bvv[ni] = bq[n0 + wc * 64 + ni * 16 + lm];
    #pragma unroll
    for (int mi = 0; mi < 2; ++mi)
      #pragma unroll
      for (int ni = 0; ni < 4; ++ni)
        #pragma unroll
        for (int r = 0; r < 4; ++r) acc[mi][ni][r] += bvv[ni];

    // f32 row-norms per head (wave spans one head's 64 cols)
    const int h = (n0 + wc * 64) >> 6;
    #pragma unroll
    for (int mi = 0; mi < 2; ++mi)
      #pragma unroll
      for (int r = 0; r < 4; ++r) {
        float s = 0.f;
        #pragma unroll
        for (int ni = 0; ni < 4; ++ni) { float v = acc[mi][ni][r]; s += v * v; }
        s += __shfl_xor(s, 1); s += __shfl_xor(s, 2);
        s += __shfl_xor(s, 4); s += __shfl_xor(s, 8);
        if (lm == 0) {
          int row = row0 + wr * 32 + mi * 16 + quad * 4 + r;
          int bb = row >> 11, ll = row & (L_DIM - 1);
          norms[(bb * H_DIM + h) * L_DIM + ll] = s;
        }
      }

    #pragma unroll
    for (int mi = 0; mi < 2; ++mi)
      #pragma unroll
      for (int r = 0; r < 4; ++r) {
        int row = row0 + wr * 32 + mi * 16 + quad * 4 + r;
        #pragma unroll
        for (int ni = 0; ni < 4; ++ni)
          Qhi[(size_t)row * D_DIM + n0 + wc * 64 + ni * 16 + lm] = (bf16_t)acc[mi][ni][r];
      }
  } else {
    // ---- K/V path: 128x128, single-bf16 ----
    const int row0 = blockIdx.y * 128;
    const bf16_t* W = (z == 2) ? Wkb : Wvb;
    bf16_t* sA = sm;           // 4096
    bf16_t* sB = sm + 4096;    // 4096
    const int wr = wave >> 1, wc = wave & 1;

    f32x4 acc[4][4];
    #pragma unroll
    for (int mi = 0; mi < 4; ++mi)
      #pragma unroll
      for (int ni = 0; ni < 4; ++ni) acc[mi][ni] = vzero;

    for (int k0 = 0; k0 < D_DIM; k0 += 32) {
      __syncthreads();
      STAGE_TILE128(xhi + (size_t)row0 * D_DIM + k0, sA);
      STAGE_TILE128(W   + (size_t)n0   * D_DIM + k0, sB);
      __syncthreads();
      bf16x8 af[4], bfr[4];
      #pragma unroll
      for (int mi = 0; mi < 4; ++mi)
        af[mi] = *reinterpret_cast<const bf16x8*>(&sA[(wr * 64 + mi * 16 + lm) * 32 + quad * 8]);
      #pragma unroll
      for (int ni = 0; ni < 4; ++ni)
        bfr[ni] = *reinterpret_cast<const bf16x8*>(&sB[(wc * 64 + ni * 16 + lm) * 32 + quad * 8]);
      #pragma unroll
      for (int mi = 0; mi < 4; ++mi)
        #pragma unroll
        for (int ni = 0; ni < 4; ++ni)
          acc[mi][ni] = __builtin_amdgcn_mfma_f32_16x16x32_bf16(af[mi], bfr[ni], acc[mi][ni], 0, 0, 0);
    }

    const float* bias = (z == 2) ? bk : bv;
    float bvv[4];
    #pragma unroll
    for (int ni = 0; ni < 4; ++ni) bvv[ni] = bias[n0 + wc * 64 + ni * 16 + lm];
    #pragma unroll
    for (int mi = 0; mi < 4; ++mi)
      #pragma unroll
      for (int ni = 0; ni < 4; ++ni)
        #pragma unroll
        for (int r = 0; r < 4; ++r) acc[mi][ni][r] += bvv[ni];

    if (z == 2) {
      #pragma unroll
      for (int mi = 0; mi < 4; ++mi)
        #pragma unroll
        for (int r = 0; r < 4; ++r) {
          int row = row0 + wr * 64 + mi * 16 + quad * 4 + r;
          #pragma unroll
          for (int ni = 0; ni < 4; ++ni)
            Khi[(size_t)row * D_DIM + n0 + wc * 64 + ni * 16 + lm] = (bf16_t)acc[mi][ni][r];
        }
    } else {
      // VT[(b*1024 + col) * 2048 + l]
      #pragma unroll
      for (int mi = 0; mi < 4; ++mi) {
        int rbase = row0 + wr * 64 + mi * 16 + quad * 4;
        int bb = rbase >> 11, l0 = rbase & (L_DIM - 1);
        #pragma unroll
        for (int ni = 0; ni < 4; ++ni) {
          int col = n0 + wc * 64 + ni * 16 + lm;
          bf16x4 wv;
          #pragma unroll
          for (int r = 0; r < 4; ++r) wv[r] = (bf16_t)acc[mi][ni][r];
          *reinterpret_cast<bf16x4*>(&VThi[((size_t)(bb * D_DIM + col)) * L_DIM + l0]) = wv;
        }
      }
    }
  }
}

// ---------------------------------------------------------------------------
// Output projection: 64x128 tiles, grid (8,64) = 2 blocks/CU.
// ---------------------------------------------------------------------------
__global__ __launch_bounds__(256) void gemm_out(
    const bf16_t* __restrict__ Ahi, const bf16_t* __restrict__ Wob,
    const float* __restrict__ bias, float* __restrict__ C)
{
  const int n0   = blockIdx.x * 128;
  const int row0 = blockIdx.y * 64;

  __shared__ __align__(16) bf16_t sm[6144];   // A 64x32 (2048) + B 128x32 (4096)

  const int tid  = threadIdx.x;
  const int lane = tid & 63;
  const int wave = tid >> 6;
  const int wr = wave >> 1, wc = wave & 1;
  const int lm = lane & 15, quad = lane >> 4;

  bf16_t* sA = sm;
  bf16_t* sB = sm + 2048;

  const f32x4 vzero = {0.f, 0.f, 0.f, 0.f};
  f32x4 acc[2][4];
  #pragma unroll
  for (int mi = 0; mi < 2; ++mi)
    #pragma unroll
    for (int ni = 0; ni < 4; ++ni) acc[mi][ni] = vzero;

  for (int k0 = 0; k0 < D_DIM; k0 += 32) {
    __syncthreads();
    STAGE_TILE64(Ahi + (size_t)row0 * D_DIM + k0, sA);
    STAGE_TILE128(Wob + (size_t)n0 * D_DIM + k0, sB);
    __syncthreads();
    bf16x8 af[2], bfr[4];
    #pragma unroll
    for (int mi = 0; mi < 2; ++mi)
      af[mi] = *reinterpret_cast<const bf16x8*>(&sA[(wr * 32 + mi * 16 + lm) * 32 + quad * 8]);
    #pragma unroll
    for (int ni = 0; ni < 4; ++ni)
      bfr[ni] = *reinterpret_cast<const bf16x8*>(&sB[(wc * 64 + ni * 16 + lm) * 32 + quad * 8]);
    #pragma unroll
    for (int mi = 0; mi < 2; ++mi)
      #pragma unroll
      for (int ni = 0; ni < 4; ++ni)
        acc[mi][ni] = __builtin_amdgcn_mfma_f32_16x16x32_bf16(af[mi], bfr[ni], acc[mi][ni], 0, 0, 0);
  }

  float bvv[4];
  #pragma unroll
  for (int ni = 0; ni < 4; ++ni) bvv[ni] = bias[n0 + wc * 64 + ni * 16 + lm];
  #pragma unroll
  for (int mi = 0; mi < 2; ++mi)
    #pragma unroll
    for (int r = 0; r < 4; ++r) {
      int row = row0 + wr * 32 + mi * 16 + quad * 4 + r;
      #pragma unroll
      for (int ni = 0; ni < 4; ++ni)
        C[(size_t)row * D_DIM + n0 + wc * 64 + ni * 16 + lm] = acc[mi][ni][r] + bvv[ni];
    }
}

// ---------------------------------------------------------------------------
// Exact top-409 per (b,h): bitonic sort (norm desc, idx asc) = lax.top_k order.
// ---------------------------------------------------------------------------
__global__ __launch_bounds__(1024) void topk_kernel(
    const float* __restrict__ norms, int* __restrict__ sel)
{
  const int bh = blockIdx.x;
  __shared__ __align__(16) float val[L_DIM];
  __shared__ __align__(16) int   idx[L_DIM];
  const int t = threadIdx.x;
  for (int i = t; i < L_DIM; i += 1024) {
    val[i] = norms[bh * L_DIM + i];
    idx[i] = i;
  }
  __syncthreads();
  for (int k = 2; k <= L_DIM; k <<= 1) {
    for (int j = k >> 1; j > 0; j >>= 1) {
      for (int i = t; i < L_DIM; i += 1024) {
        int ixj = i ^ j;
        if (ixj > i) {
          float v1 = val[i], v2 = val[ixj];
          int   i1 = idx[i], i2 = idx[ixj];
          bool up = ((i & k) == 0);
          bool sw = up ? ((v2 > v1) || (v2 == v1 && i2 < i1))
                       : ((v1 > v2) || (v1 == v2 && i1 < i2));
          if (sw) { val[i] = v2; val[ixj] = v1; idx[i] = i2; idx[ixj] = i1; }
        }
      }
      __syncthreads();
    }
  }
  for (int i = t; i < SLOTS; i += 1024)
    sel[bh * SLOTS + i] = (i < KTOP) ? idx[i] : -1;
}

// ---------------------------------------------------------------------------
// K-split flash attention, single-bf16 Q/K/V. Block = 4 waves x 16 q-slots;
// keys [ks*512, +512). NO barriers: the P LDS round-trip is wave-private
// (sPh indexed [wave]) — intra-wave LDS ordering is lgkmcnt-guaranteed.
// ---------------------------------------------------------------------------
__global__ __launch_bounds__(256) void attn_kernel(
    const bf16_t* __restrict__ Qhi,
    const bf16_t* __restrict__ Khi,
    const bf16_t* __restrict__ VThi,
    const int* __restrict__ sel,
    float* __restrict__ Ol, float* __restrict__ Oo)
{
  const int bx = blockIdx.x;
  const int bh = bx & 31;
  const int t2 = bx >> 5;
  const int qc = t2 % 7;
  const int ks = t2 / 7;
  const int b = bh >> 4, h = bh & 15;
  const int wave = threadIdx.x >> 6;
  const int lane = threadIdx.x & 63;
  const int lm = lane & 15, quad = lane >> 4;

  __shared__ __align__(16) bf16_t sPh[4][16][40];

  const int qbase = qc * 64 + wave * 16;
  const int qi = sel[bh * SLOTS + qbase + lm];
  const size_t qo = ((size_t)(b * L_DIM + (qi >= 0 ? qi : 0))) * D_DIM + h * 64;
  const bf16x8 qa0 = *reinterpret_cast<const bf16x8*>(&Qhi[qo + quad * 8]);
  const bf16x8 qa1 = *reinterpret_cast<const bf16x8*>(&Qhi[qo + 32 + quad * 8]);

  const f32x4 vzero = {0.f, 0.f, 0.f, 0.f};
  float l_l[4] = {0.f, 0.f, 0.f, 0.f};
  f32x4 o[4];
  #pragma unroll
  for (int ni = 0; ni < 4; ++ni) o[ni] = vzero;

  const float scale = 0.125f;
  const size_t kbase = (size_t)(b * L_DIM) * D_DIM + h * 64;
  const int key0 = ks * KCHUNK;

  for (int kt = 0; kt < KCHUNK; kt += 32) {
    f32x4 s0 = vzero, s1 = vzero;
    {
      size_t kr0 = kbase + (size_t)(key0 + kt + lm) * D_DIM;
      bf16x8 kb0 = *reinterpret_cast<const bf16x8*>(&Khi[kr0 + quad * 8]);
      bf16x8 kb1 = *reinterpret_cast<const bf16x8*>(&Khi[kr0 + 32 + quad * 8]);
      s0 = __builtin_amdgcn_mfma_f32_16x16x32_bf16(qa0, kb0, s0, 0, 0, 0);
      s0 = __builtin_amdgcn_mfma_f32_16x16x32_bf16(qa1, kb1, s0, 0, 0, 0);
      size_t kr1 = kbase + (size_t)(key0 + kt + 16 + lm) * D_DIM;
      bf16x8 kb2 = *reinterpret_cast<const bf16x8*>(&Khi[kr1 + quad * 8]);
      bf16x8 kb3 = *reinterpret_cast<const bf16x8*>(&Khi[kr1 + 32 + quad * 8]);
      s1 = __builtin_amdgcn_mfma_f32_16x16x32_bf16(qa0, kb2, s1, 0, 0, 0);
      s1 = __builtin_amdgcn_mfma_f32_16x16x32_bf16(qa1, kb3, s1, 0, 0, 0);
    }
    #pragma unroll
    for (int r = 0; r < 4; ++r) {
      float p0 = __expf(s0[r] * scale);
      float p1 = __expf(s1[r] * scale);
      l_l[r] += p0 + p1;
      sPh[wave][quad * 4 + r][lm]      = (bf16_t)p0;
      sPh[wave][quad * 4 + r][16 + lm] = (bf16_t)p1;
    }
    bf16x8 pah = *reinterpret_cast<const bf16x8*>(&sPh[wave][lm][quad * 8]);
    #pragma unroll
    for (int ni = 0; ni < 4; ++ni) {
      size_t vo = ((size_t)(b * D_DIM + h * 64 + ni * 16 + lm)) * L_DIM + key0 + kt + quad * 8;
      const bf16x8 vbh = *reinterpret_cast<const bf16x8*>(&VThi[vo]);
      o[ni] = __builtin_amdgcn_mfma_f32_16x16x32_bf16(pah, vbh, o[ni], 0, 0, 0);
    }
  }

  #pragma unroll
  for (int r = 0; r < 4; ++r) {
    l_l[r] += __shfl_xor(l_l[r], 1);
    l_l[r] += __shfl_xor(l_l[r], 2);
    l_l[r] += __shfl_xor(l_l[r], 4);
    l_l[r] += __shfl_xor(l_l[r], 8);
  }

  #pragma unroll
  for (int r = 0; r < 4; ++r) {
    int slot = qbase + quad * 4 + r;
    int s2 = sel[bh * SLOTS + slot];
    if (s2 >= 0) {
      size_t gs = (size_t)(bh * SLOTS + slot) * KSPLIT + ks;
      if (lm == 0) Ol[gs] = l_l[r];
      #pragma unroll
      for (int ni = 0; ni < 4; ++ni)
        Oo[gs * 64 + ni * 16 + lm] = o[ni][r];
    }
  }
}

// ---------------------------------------------------------------------------
// Combine ksplit partials -> AO (selected rows; meanfill covered the rest).
// ---------------------------------------------------------------------------
__global__ __launch_bounds__(256) void combine_kernel(
    const float* __restrict__ Ol, const float* __restrict__ Oo,
    const int* __restrict__ sel, bf16_t* __restrict__ AOhi)
{
  const int bh = blockIdx.x;
  const int b = bh >> 4, h = bh & 15;
  const int chunk = blockIdx.y;
  const int tid = threadIdx.x;
  const int dim = tid & 63;
  const int sl  = tid >> 6;
  #pragma unroll
  for (int p = 0; p < 4; ++p) {
    int slot = chunk * 16 + p * 4 + sl;
    int qi = sel[bh * SLOTS + slot];
    if (qi < 0) continue;
    size_t gs = (size_t)(bh * SLOTS + slot) * KSPLIT;
    float L = Ol[gs] + Ol[gs + 1] + Ol[gs + 2] + Ol[gs + 3];
    float ov = Oo[gs * 64 + dim] + Oo[(gs + 1) * 64 + dim]
             + Oo[(gs + 2) * 64 + dim] + Oo[(gs + 3) * 64 + dim];
    AOhi[((size_t)(b * L_DIM + qi)) * D_DIM + h * 64 + dim] = (bf16_t)(ov / L);
  }
}

// ---------------------------------------------------------------------------
// mean(V) to EVERY AO row; combine overwrites selected rows.
// ---------------------------------------------------------------------------
__global__ __launch_bounds__(256) void meanfill_kernel(
    const bf16_t* __restrict__ VThi, bf16_t* __restrict__ AOhi)
{
  const int bh = blockIdx.x;
  const int b = bh >> 4, h = bh & 15;
  const int t = threadIdx.x;
  __shared__ __align__(16) bf16_t smh[64];
  {
    const int hd = t >> 2, part = t & 3;
    size_t base = ((size_t)(b * D_DIM + h * 64 + hd)) * L_DIM;
    float s = 0.f;
    for (int l0 = part * 512; l0 < part * 512 + 512; l0 += 8) {
      bf16x8 vh = *reinterpret_cast<const bf16x8*>(&VThi[base + l0]);
      #pragma unroll
      for (int j = 0; j < 8; ++j) s += (float)vh[j];
    }
    s += __shfl_xor(s, 1);
    s += __shfl_xor(s, 2);
    if (part == 0) smh[hd] = (bf16_t)(s * (1.0f / (float)L_DIM));
  }
  __syncthreads();
  const int lbase = blockIdx.y * 256;
  for (int i = t; i < 256 * 64; i += 256) {
    int l = lbase + (i >> 6), hd = i & 63;
    AOhi[((size_t)(b * L_DIM + l)) * D_DIM + h * 64 + hd] = smh[hd];
  }
}

// ---------------------------------------------------------------------------
extern "C" void kernel_launch(void* const* d_in, const int* in_sizes, int n_in,
                              void* d_out, int out_size, void* d_ws, size_t ws_size,
                              hipStream_t stream) {
  const float* x  = (const float*)d_in[0];
  const float* Wq = (const float*)d_in[1];
  const float* bq = (const float*)d_in[2];
  const float* Wk = (const float*)d_in[3];
  const float* bk = (const float*)d_in[4];
  const float* Wv = (const float*)d_in[5];
  const float* bv = (const float*)d_in[6];
  const float* Wo = (const float*)d_in[7];
  const float* bo = (const float*)d_in[8];
  float* out = (float*)d_out;

  // ws layout (~42.6 MB):
  //  [0,8)    Qhi  (aliased as AOhi after attn)
  //  [8,16)   VThi
  //  [16,24)  xhi  -+ dead after gemm_qkv; region [16,32) reused for Oo
  //  [24,32)  xlo  -+
  //  [32,34)  Wqhi  [34,36) Wqlo  [36,38) Wkb  [38,40) Wvb  [40,42) Wob
  //  [42,..)  norms (256 KB), sel (57 KB), Ol (229 KB)
  // Khi lives in d_out (8 of 16 MB) — dead until gemm_out rewrites d_out.
  const size_t MB = 1u << 20;
  char* ws = (char*)d_ws;
  bf16_t* Qhi  = (bf16_t*)(ws);
  bf16_t* VThi = (bf16_t*)(ws + 8 * MB);
  bf16_t* xhi  = (bf16_t*)(ws + 16 * MB);
  bf16_t* xlo  = (bf16_t*)(ws + 24 * MB);
  float*  Oo   = (float*)(ws + 16 * MB);          // aliases xhi/xlo (14.7 MB)
  bf16_t* Wqhi = (bf16_t*)(ws + 32 * MB);
  bf16_t* Wqlo = (bf16_t*)(ws + 34 * MB);
  bf16_t* Wkb  = (bf16_t*)(ws + 36 * MB);
  bf16_t* Wvb  = (bf16_t*)(ws + 38 * MB);
  bf16_t* Wob  = (bf16_t*)(ws + 40 * MB);
  float*  norms = (float*)(ws + 42 * MB);
  int*    sel   = (int*)(ws + 42 * MB + (256u << 10));
  float*  Ol    = (float*)(ws + 42 * MB + (320u << 10));
  bf16_t* AOhi = Qhi;
  bf16_t* Khi = (bf16_t*)d_out;

  dim3 blk(256);
  prep_kernel<<<dim3(8192), blk, 0, stream>>>(x, Wq, Wk, Wv, Wo,
                                              xhi, xlo, Wqhi, Wqlo, Wkb, Wvb, Wob);
  gemm_qkv<<<dim3(8, 32, 4), blk, 0, stream>>>(xhi, xlo, Wqhi, Wqlo, Wkb, Wvb,
                                               bq, bk, bv, Qhi, Khi, VThi, norms);
  topk_kernel<<<dim3(32), dim3(1024), 0, stream>>>(norms, sel);
  attn_kernel<<<dim3(32 * 7 * KSPLIT), blk, 0, stream>>>(Qhi, Khi, VThi, sel, Ol, Oo);
  meanfill_kernel<<<dim3(32, 8), blk, 0, stream>>>(VThi, AOhi);
  combine_kernel<<<dim3(32, 28), blk, 0, stream>>>(Ol, Oo, sel, AOhi);
  gemm_out<<<dim3(8, 64), blk, 0, stream>>>(AOhi, Wob, bo, out);
}

// Round 8
// 305.644 us; speedup vs baseline: 1.8894x; 1.0094x over previous
//
#include <hip/hip_runtime.h>
#include <hip/hip_bf16.h>
#include <math.h>

typedef __bf16 bf16_t;
typedef __bf16 bf16x8 __attribute__((ext_vector_type(8)));
typedef __bf16 bf16x4 __attribute__((ext_vector_type(4)));
typedef float  f32x4  __attribute__((ext_vector_type(4)));

#define L_DIM 2048
#define D_DIM 1024
#define H_DIM 16
#define M_DIM 4096
#define KTOP 409
#define SLOTS 448    // 7 * 64, padded (sel = -1 beyond KTOP)
#define KSPLIT 8
#define KCHUNK 256   // L_DIM / KSPLIT

// split f32 into bf16 hi + bf16 lo (a ~= hi + lo)
__device__ __forceinline__ void split2(float a, bf16_t& h, bf16_t& l) {
  h = (bf16_t)a;
  l = (bf16_t)(a - (float)h);
}

// async global -> LDS, 16B per lane; lds ptr must be wave-uniform (m104/m108)
__device__ __forceinline__ void gld16(const bf16_t* g, bf16_t* l) {
  __builtin_amdgcn_global_load_lds(
      (const __attribute__((address_space(1))) void*)g,
      (__attribute__((address_space(3))) void*)l, 16, 0, 0);
}

// stage a 128x32 bf16 tile (row stride D_DIM) into unpadded LDS.
// wave w covers segments {2w, 2w+1}; seg s = rows 16s..16s+15.
#define STAGE_TILE128(src, dst)                                               \
  {                                                                           \
    const int seg0 = wave * 2;                                                \
    const int r0 = seg0 * 16 + (lane >> 2);                                   \
    const int c0 = (lane & 3) * 8;                                            \
    gld16((src) + (size_t)r0 * D_DIM + c0, (dst) + seg0 * 512);               \
    gld16((src) + (size_t)(r0 + 16) * D_DIM + c0, (dst) + (seg0 + 1) * 512);  \
  }

// stage a 64x32 bf16 tile: one 16-row segment per wave.
#define STAGE_TILE64(src, dst)                                                \
  {                                                                           \
    const int r0 = wave * 16 + (lane >> 2);                                   \
    const int c0 = (lane & 3) * 8;                                            \
    gld16((src) + (size_t)r0 * D_DIM + c0, (dst) + wave * 512);               \
  }

// ---------------------------------------------------------------------------
// prep: pre-split x and Wq into bf16 hi/lo; pre-round Wk/Wv/Wo to bf16.
// ---------------------------------------------------------------------------
__global__ __launch_bounds__(256) void prep_kernel(
    const float* __restrict__ x,  const float* __restrict__ Wq,
    const float* __restrict__ Wk, const float* __restrict__ Wv,
    const float* __restrict__ Wo,
    bf16_t* __restrict__ xhi, bf16_t* __restrict__ xlo,
    bf16_t* __restrict__ Wqhi, bf16_t* __restrict__ Wqlo,
    bf16_t* __restrict__ Wkb,  bf16_t* __restrict__ Wvb,
    bf16_t* __restrict__ Wob)
{
  const int XV = (M_DIM * D_DIM) / 4;
  const int WV = (D_DIM * D_DIM) / 4;
  int i = blockIdx.x * 256 + threadIdx.x;
  if (i < XV) {
    f32x4 v = ((const f32x4*)x)[i];
    bf16x4 h, l;
    #pragma unroll
    for (int j = 0; j < 4; ++j) { bf16_t hh, ll; split2(v[j], hh, ll); h[j] = hh; l[j] = ll; }
    ((bf16x4*)xhi)[i] = h;
    ((bf16x4*)xlo)[i] = l;
  } else if (i < XV + WV) {
    int j0 = i - XV;
    f32x4 v = ((const f32x4*)Wq)[j0];
    bf16x4 h, l;
    #pragma unroll
    for (int j = 0; j < 4; ++j) { bf16_t hh, ll; split2(v[j], hh, ll); h[j] = hh; l[j] = ll; }
    ((bf16x4*)Wqhi)[j0] = h;
    ((bf16x4*)Wqlo)[j0] = l;
  } else if (i < XV + 2 * WV) {
    int j0 = i - XV - WV;
    f32x4 v = ((const f32x4*)Wk)[j0];
    bf16x4 h;
    #pragma unroll
    for (int j = 0; j < 4; ++j) h[j] = (bf16_t)v[j];
    ((bf16x4*)Wkb)[j0] = h;
  } else if (i < XV + 3 * WV) {
    int j0 = i - XV - 2 * WV;
    f32x4 v = ((const f32x4*)Wv)[j0];
    bf16x4 h;
    #pragma unroll
    for (int j = 0; j < 4; ++j) h[j] = (bf16_t)v[j];
    ((bf16x4*)Wvb)[j0] = h;
  } else {
    int j0 = i - XV - 3 * WV;
    f32x4 v = ((const f32x4*)Wo)[j0];
    bf16x4 h;
    #pragma unroll
    for (int j = 0; j < 4; ++j) h[j] = (bf16_t)v[j];
    ((bf16x4*)Wob)[j0] = h;
  }
}

// ---------------------------------------------------------------------------
// Fused QKV projections, async staging (round-6 structure, best measured).
// z=0: Q 128x128 split-bf16 3-product + f32 norms; z=1: K; z=2: V transposed.
// ---------------------------------------------------------------------------
__global__ __launch_bounds__(256) void gemm_qkv(
    const bf16_t* __restrict__ xhi, const bf16_t* __restrict__ xlo,
    const bf16_t* __restrict__ Wqhi, const bf16_t* __restrict__ Wqlo,
    const bf16_t* __restrict__ Wkb, const bf16_t* __restrict__ Wvb,
    const float* __restrict__ bq, const float* __restrict__ bk, const float* __restrict__ bv,
    bf16_t* __restrict__ Qhi, bf16_t* __restrict__ Khi, bf16_t* __restrict__ VThi,
    float* __restrict__ norms)
{
  const int z = blockIdx.z;
  const int n0   = blockIdx.x * 128;
  const int row0 = blockIdx.y * 128;

  __shared__ __align__(16) bf16_t sm[4][4096];

  const int tid  = threadIdx.x;
  const int lane = tid & 63;
  const int wave = tid >> 6;
  const int wr = wave >> 1, wc = wave & 1;
  const int lm = lane & 15, quad = lane >> 4;

  const f32x4 vzero = {0.f, 0.f, 0.f, 0.f};
  f32x4 acc[4][4];
  #pragma unroll
  for (int mi = 0; mi < 4; ++mi)
    #pragma unroll
    for (int ni = 0; ni < 4; ++ni) acc[mi][ni] = vzero;

  if (z == 0) {
    for (int k0 = 0; k0 < D_DIM; k0 += 32) {
      __syncthreads();
      STAGE_TILE128(xhi  + (size_t)row0 * D_DIM + k0, sm[0]);
      STAGE_TILE128(xlo  + (size_t)row0 * D_DIM + k0, sm[1]);
      STAGE_TILE128(Wqhi + (size_t)n0   * D_DIM + k0, sm[2]);
      STAGE_TILE128(Wqlo + (size_t)n0   * D_DIM + k0, sm[3]);
      __syncthreads();
      bf16x8 afh[4], afl[4], bfh[4], bfl[4];
      #pragma unroll
      for (int mi = 0; mi < 4; ++mi) {
        afh[mi] = *reinterpret_cast<const bf16x8*>(&sm[0][(wr * 64 + mi * 16 + lm) * 32 + quad * 8]);
        afl[mi] = *reinterpret_cast<const bf16x8*>(&sm[1][(wr * 64 + mi * 16 + lm) * 32 + quad * 8]);
      }
      #pragma unroll
      for (int ni = 0; ni < 4; ++ni) {
        bfh[ni] = *reinterpret_cast<const bf16x8*>(&sm[2][(wc * 64 + ni * 16 + lm) * 32 + quad * 8]);
        bfl[ni] = *reinterpret_cast<const bf16x8*>(&sm[3][(wc * 64 + ni * 16 + lm) * 32 + quad * 8]);
      }
      #pragma unroll
      for (int mi = 0; mi < 4; ++mi)
        #pragma unroll
        for (int ni = 0; ni < 4; ++ni) {
          acc[mi][ni] = __builtin_amdgcn_mfma_f32_16x16x32_bf16(afh[mi], bfh[ni], acc[mi][ni], 0, 0, 0);
          acc[mi][ni] = __builtin_amdgcn_mfma_f32_16x16x32_bf16(afh[mi], bfl[ni], acc[mi][ni], 0, 0, 0);
          acc[mi][ni] = __builtin_amdgcn_mfma_f32_16x16x32_bf16(afl[mi], bfh[ni], acc[mi][ni], 0, 0, 0);
        }
    }

    float bvv[4];
    #pragma unroll
    for (int ni = 0; ni < 4; ++ni) bvv[ni] = bq[n0 + wc * 64 + ni * 16 + lm];
    #pragma unroll
    for (int mi = 0; mi < 4; ++mi)
      #pragma unroll
      for (int ni = 0; ni < 4; ++ni)
        #pragma unroll
        for (int r = 0; r < 4; ++r) acc[mi][ni][r] += bvv[ni];

    const int h = (n0 + wc * 64) >> 6;
    #pragma unroll
    for (int mi = 0; mi < 4; ++mi)
      #pragma unroll
      for (int r = 0; r < 4; ++r) {
        float s = 0.f;
        #pragma unroll
        for (int ni = 0; ni < 4; ++ni) { float v = acc[mi][ni][r]; s += v * v; }
        s += __shfl_xor(s, 1); s += __shfl_xor(s, 2);
        s += __shfl_xor(s, 4); s += __shfl_xor(s, 8);
        if (lm == 0) {
          int row = row0 + wr * 64 + mi * 16 + quad * 4 + r;
          int bb = row >> 11, ll = row & (L_DIM - 1);
          norms[(bb * H_DIM + h) * L_DIM + ll] = s;
        }
      }

    #pragma unroll
    for (int mi = 0; mi < 4; ++mi)
      #pragma unroll
      for (int r = 0; r < 4; ++r) {
        int row = row0 + wr * 64 + mi * 16 + quad * 4 + r;
        #pragma unroll
        for (int ni = 0; ni < 4; ++ni)
          Qhi[(size_t)row * D_DIM + n0 + wc * 64 + ni * 16 + lm] = (bf16_t)acc[mi][ni][r];
      }
  } else {
    const bf16_t* W = (z == 1) ? Wkb : Wvb;
    for (int k0 = 0; k0 < D_DIM; k0 += 32) {
      __syncthreads();
      STAGE_TILE128(xhi + (size_t)row0 * D_DIM + k0, sm[0]);
      STAGE_TILE128(W   + (size_t)n0   * D_DIM + k0, sm[2]);
      __syncthreads();
      bf16x8 af[4], bfr[4];
      #pragma unroll
      for (int mi = 0; mi < 4; ++mi)
        af[mi] = *reinterpret_cast<const bf16x8*>(&sm[0][(wr * 64 + mi * 16 + lm) * 32 + quad * 8]);
      #pragma unroll
      for (int ni = 0; ni < 4; ++ni)
        bfr[ni] = *reinterpret_cast<const bf16x8*>(&sm[2][(wc * 64 + ni * 16 + lm) * 32 + quad * 8]);
      #pragma unroll
      for (int mi = 0; mi < 4; ++mi)
        #pragma unroll
        for (int ni = 0; ni < 4; ++ni)
          acc[mi][ni] = __builtin_amdgcn_mfma_f32_16x16x32_bf16(af[mi], bfr[ni], acc[mi][ni], 0, 0, 0);
    }

    const float* bias = (z == 1) ? bk : bv;
    float bvv[4];
    #pragma unroll
    for (int ni = 0; ni < 4; ++ni) bvv[ni] = bias[n0 + wc * 64 + ni * 16 + lm];
    #pragma unroll
    for (int mi = 0; mi < 4; ++mi)
      #pragma unroll
      for (int ni = 0; ni < 4; ++ni)
        #pragma unroll
        for (int r = 0; r < 4; ++r) acc[mi][ni][r] += bvv[ni];

    if (z == 1) {
      #pragma unroll
      for (int mi = 0; mi < 4; ++mi)
        #pragma unroll
        for (int r = 0; r < 4; ++r) {
          int row = row0 + wr * 64 + mi * 16 + quad * 4 + r;
          #pragma unroll
          for (int ni = 0; ni < 4; ++ni)
            Khi[(size_t)row * D_DIM + n0 + wc * 64 + ni * 16 + lm] = (bf16_t)acc[mi][ni][r];
        }
    } else {
      #pragma unroll
      for (int mi = 0; mi < 4; ++mi) {
        int rbase = row0 + wr * 64 + mi * 16 + quad * 4;
        int bb = rbase >> 11, l0 = rbase & (L_DIM - 1);
        #pragma unroll
        for (int ni = 0; ni < 4; ++ni) {
          int col = n0 + wc * 64 + ni * 16 + lm;
          bf16x4 wv;
          #pragma unroll
          for (int r = 0; r < 4; ++r) wv[r] = (bf16_t)acc[mi][ni][r];
          *reinterpret_cast<bf16x4*>(&VThi[((size_t)(bb * D_DIM + col)) * L_DIM + l0]) = wv;
        }
      }
    }
  }
}

// ---------------------------------------------------------------------------
// Output projection: 64x128 tiles, grid (8,64) = 2 blocks/CU.
// ---------------------------------------------------------------------------
__global__ __launch_bounds__(256) void gemm_out(
    const bf16_t* __restrict__ Ahi, const bf16_t* __restrict__ Wob,
    const float* __restrict__ bias, float* __restrict__ C)
{
  const int n0   = blockIdx.x * 128;
  const int row0 = blockIdx.y * 64;

  __shared__ __align__(16) bf16_t sm[6144];

  const int tid  = threadIdx.x;
  const int lane = tid & 63;
  const int wave = tid >> 6;
  const int wr = wave >> 1, wc = wave & 1;
  const int lm = lane & 15, quad = lane >> 4;

  bf16_t* sA = sm;
  bf16_t* sB = sm + 2048;

  const f32x4 vzero = {0.f, 0.f, 0.f, 0.f};
  f32x4 acc[2][4];
  #pragma unroll
  for (int mi = 0; mi < 2; ++mi)
    #pragma unroll
    for (int ni = 0; ni < 4; ++ni) acc[mi][ni] = vzero;

  for (int k0 = 0; k0 < D_DIM; k0 += 32) {
    __syncthreads();
    STAGE_TILE64(Ahi + (size_t)row0 * D_DIM + k0, sA);
    STAGE_TILE128(Wob + (size_t)n0 * D_DIM + k0, sB);
    __syncthreads();
    bf16x8 af[2], bfr[4];
    #pragma unroll
    for (int mi = 0; mi < 2; ++mi)
      af[mi] = *reinterpret_cast<const bf16x8*>(&sA[(wr * 32 + mi * 16 + lm) * 32 + quad * 8]);
    #pragma unroll
    for (int ni = 0; ni < 4; ++ni)
      bfr[ni] = *reinterpret_cast<const bf16x8*>(&sB[(wc * 64 + ni * 16 + lm) * 32 + quad * 8]);
    #pragma unroll
    for (int mi = 0; mi < 2; ++mi)
      #pragma unroll
      for (int ni = 0; ni < 4; ++ni)
        acc[mi][ni] = __builtin_amdgcn_mfma_f32_16x16x32_bf16(af[mi], bfr[ni], acc[mi][ni], 0, 0, 0);
  }

  float bvv[4];
  #pragma unroll
  for (int ni = 0; ni < 4; ++ni) bvv[ni] = bias[n0 + wc * 64 + ni * 16 + lm];
  #pragma unroll
  for (int mi = 0; mi < 2; ++mi)
    #pragma unroll
    for (int r = 0; r < 4; ++r) {
      int row = row0 + wr * 32 + mi * 16 + quad * 4 + r;
      #pragma unroll
      for (int ni = 0; ni < 4; ++ni)
        C[(size_t)row * D_DIM + n0 + wc * 64 + ni * 16 + lm] = acc[mi][ni][r] + bvv[ni];
    }
}

// ---------------------------------------------------------------------------
// Exact top-409 per (b,h): bitonic sort (norm desc, idx asc) = lax.top_k set.
// ---------------------------------------------------------------------------
__global__ __launch_bounds__(1024) void topk_kernel(
    const float* __restrict__ norms, int* __restrict__ sel)
{
  const int bh = blockIdx.x;
  __shared__ __align__(16) float val[L_DIM];
  __shared__ __align__(16) int   idx[L_DIM];
  const int t = threadIdx.x;
  for (int i = t; i < L_DIM; i += 1024) {
    val[i] = norms[bh * L_DIM + i];
    idx[i] = i;
  }
  __syncthreads();
  for (int k = 2; k <= L_DIM; k <<= 1) {
    for (int j = k >> 1; j > 0; j >>= 1) {
      for (int i = t; i < L_DIM; i += 1024) {
        int ixj = i ^ j;
        if (ixj > i) {
          float v1 = val[i], v2 = val[ixj];
          int   i1 = idx[i], i2 = idx[ixj];
          bool up = ((i & k) == 0);
          bool sw = up ? ((v2 > v1) || (v2 == v1 && i2 < i1))
                       : ((v1 > v2) || (v1 == v2 && i1 < i2));
          if (sw) { val[i] = v2; val[ixj] = v1; idx[i] = i2; idx[ixj] = i1; }
        }
      }
      __syncthreads();
    }
  }
  for (int i = t; i < SLOTS; i += 1024)
    sel[bh * SLOTS + i] = (i < KTOP) ? idx[i] : -1;
}

// ---------------------------------------------------------------------------
// K-split flash attention, single-bf16 Q/K/V. Block = 4 waves x 16 q-slots;
// keys [ks*256, +256). KSPLIT=8 -> 1792 blocks = 7/CU = 28 waves/CU for
// latency hiding. V loads hoisted before softmax (independent of scores).
// No barriers: sPh is wave-private. Partials: Ol f32, Oo bf16.
// ---------------------------------------------------------------------------
__global__ __launch_bounds__(256) void attn_kernel(
    const bf16_t* __restrict__ Qhi,
    const bf16_t* __restrict__ Khi,
    const bf16_t* __restrict__ VThi,
    const int* __restrict__ sel,
    float* __restrict__ Ol, bf16_t* __restrict__ Oo)
{
  const int bx = blockIdx.x;
  const int bh = bx & 31;
  const int t2 = bx >> 5;
  const int qc = t2 % 7;
  const int ks = t2 / 7;
  const int b = bh >> 4, h = bh & 15;
  const int wave = threadIdx.x >> 6;
  const int lane = threadIdx.x & 63;
  const int lm = lane & 15, quad = lane >> 4;

  __shared__ __align__(16) bf16_t sPh[4][16][40];

  const int qbase = qc * 64 + wave * 16;
  const int qi = sel[bh * SLOTS + qbase + lm];
  const size_t qo = ((size_t)(b * L_DIM + (qi >= 0 ? qi : 0))) * D_DIM + h * 64;
  const bf16x8 qa0 = *reinterpret_cast<const bf16x8*>(&Qhi[qo + quad * 8]);
  const bf16x8 qa1 = *reinterpret_cast<const bf16x8*>(&Qhi[qo + 32 + quad * 8]);

  const f32x4 vzero = {0.f, 0.f, 0.f, 0.f};
  float l_l[4] = {0.f, 0.f, 0.f, 0.f};
  f32x4 o[4];
  #pragma unroll
  for (int ni = 0; ni < 4; ++ni) o[ni] = vzero;

  const float scale = 0.125f;
  const size_t kbase = (size_t)(b * L_DIM) * D_DIM + h * 64;
  const int key0 = ks * KCHUNK;

  for (int kt = 0; kt < KCHUNK; kt += 32) {
    // issue K loads
    size_t kr0 = kbase + (size_t)(key0 + kt + lm) * D_DIM;
    size_t kr1 = kbase + (size_t)(key0 + kt + 16 + lm) * D_DIM;
    bf16x8 kb0 = *reinterpret_cast<const bf16x8*>(&Khi[kr0 + quad * 8]);
    bf16x8 kb1 = *reinterpret_cast<const bf16x8*>(&Khi[kr0 + 32 + quad * 8]);
    bf16x8 kb2 = *reinterpret_cast<const bf16x8*>(&Khi[kr1 + quad * 8]);
    bf16x8 kb3 = *reinterpret_cast<const bf16x8*>(&Khi[kr1 + 32 + quad * 8]);
    // issue V loads early (independent of scores -> stay in flight over exp)
    bf16x8 vbh[4];
    #pragma unroll
    for (int ni = 0; ni < 4; ++ni) {
      size_t vo = ((size_t)(b * D_DIM + h * 64 + ni * 16 + lm)) * L_DIM + key0 + kt + quad * 8;
      vbh[ni] = *reinterpret_cast<const bf16x8*>(&VThi[vo]);
    }
    f32x4 s0 = vzero, s1 = vzero;
    s0 = __builtin_amdgcn_mfma_f32_16x16x32_bf16(qa0, kb0, s0, 0, 0, 0);
    s0 = __builtin_amdgcn_mfma_f32_16x16x32_bf16(qa1, kb1, s0, 0, 0, 0);
    s1 = __builtin_amdgcn_mfma_f32_16x16x32_bf16(qa0, kb2, s1, 0, 0, 0);
    s1 = __builtin_amdgcn_mfma_f32_16x16x32_bf16(qa1, kb3, s1, 0, 0, 0);
    #pragma unroll
    for (int r = 0; r < 4; ++r) {
      float p0 = __expf(s0[r] * scale);
      float p1 = __expf(s1[r] * scale);
      l_l[r] += p0 + p1;
      sPh[wave][quad * 4 + r][lm]      = (bf16_t)p0;
      sPh[wave][quad * 4 + r][16 + lm] = (bf16_t)p1;
    }
    bf16x8 pah = *reinterpret_cast<const bf16x8*>(&sPh[wave][lm][quad * 8]);
    #pragma unroll
    for (int ni = 0; ni < 4; ++ni)
      o[ni] = __builtin_amdgcn_mfma_f32_16x16x32_bf16(pah, vbh[ni], o[ni], 0, 0, 0);
  }

  #pragma unroll
  for (int r = 0; r < 4; ++r) {
    l_l[r] += __shfl_xor(l_l[r], 1);
    l_l[r] += __shfl_xor(l_l[r], 2);
    l_l[r] += __shfl_xor(l_l[r], 4);
    l_l[r] += __shfl_xor(l_l[r], 8);
  }

  #pragma unroll
  for (int r = 0; r < 4; ++r) {
    int slot = qbase + quad * 4 + r;
    int s2 = sel[bh * SLOTS + slot];
    if (s2 >= 0) {
      size_t gs = (size_t)(bh * SLOTS + slot) * KSPLIT + ks;
      if (lm == 0) Ol[gs] = l_l[r];
      #pragma unroll
      for (int ni = 0; ni < 4; ++ni)
        Oo[gs * 64 + ni * 16 + lm] = (bf16_t)o[ni][r];
    }
  }
}

// ---------------------------------------------------------------------------
// Combine ksplit partials -> AO (selected rows; meanfill covered the rest).
// ---------------------------------------------------------------------------
__global__ __launch_bounds__(256) void combine_kernel(
    const float* __restrict__ Ol, const bf16_t* __restrict__ Oo,
    const int* __restrict__ sel, bf16_t* __restrict__ AOhi)
{
  const int bh = blockIdx.x;
  const int b = bh >> 4, h = bh & 15;
  const int chunk = blockIdx.y;
  const int tid = threadIdx.x;
  const int dim = tid & 63;
  const int sl  = tid >> 6;
  #pragma unroll
  for (int p = 0; p < 4; ++p) {
    int slot = chunk * 16 + p * 4 + sl;
    int qi = sel[bh * SLOTS + slot];
    if (qi < 0) continue;
    size_t gs = (size_t)(bh * SLOTS + slot) * KSPLIT;
    float L = 0.f, ov = 0.f;
    #pragma unroll
    for (int s = 0; s < KSPLIT; ++s) {
      L  += Ol[gs + s];
      ov += (float)Oo[(gs + s) * 64 + dim];
    }
    AOhi[((size_t)(b * L_DIM + qi)) * D_DIM + h * 64 + dim] = (bf16_t)(ov / L);
  }
}

// ---------------------------------------------------------------------------
// mean(V) to EVERY AO row; combine overwrites selected rows.
// ---------------------------------------------------------------------------
__global__ __launch_bounds__(256) void meanfill_kernel(
    const bf16_t* __restrict__ VThi, bf16_t* __restrict__ AOhi)
{
  const int bh = blockIdx.x;
  const int b = bh >> 4, h = bh & 15;
  const int t = threadIdx.x;
  __shared__ __align__(16) bf16_t smh[64];
  {
    const int hd = t >> 2, part = t & 3;
    size_t base = ((size_t)(b * D_DIM + h * 64 + hd)) * L_DIM;
    float s = 0.f;
    for (int l0 = part * 512; l0 < part * 512 + 512; l0 += 8) {
      bf16x8 vh = *reinterpret_cast<const bf16x8*>(&VThi[base + l0]);
      #pragma unroll
      for (int j = 0; j < 8; ++j) s += (float)vh[j];
    }
    s += __shfl_xor(s, 1);
    s += __shfl_xor(s, 2);
    if (part == 0) smh[hd] = (bf16_t)(s * (1.0f / (float)L_DIM));
  }
  __syncthreads();
  const int lbase = blockIdx.y * 256;
  for (int i = t; i < 256 * 64; i += 256) {
    int l = lbase + (i >> 6), hd = i & 63;
    AOhi[((size_t)(b * L_DIM + l)) * D_DIM + h * 64 + hd] = smh[hd];
  }
}

// ---------------------------------------------------------------------------
extern "C" void kernel_launch(void* const* d_in, const int* in_sizes, int n_in,
                              void* d_out, int out_size, void* d_ws, size_t ws_size,
                              hipStream_t stream) {
  const float* x  = (const float*)d_in[0];
  const float* Wq = (const float*)d_in[1];
  const float* bq = (const float*)d_in[2];
  const float* Wk = (const float*)d_in[3];
  const float* bk = (const float*)d_in[4];
  const float* Wv = (const float*)d_in[5];
  const float* bv = (const float*)d_in[6];
  const float* Wo = (const float*)d_in[7];
  const float* bo = (const float*)d_in[8];
  float* out = (float*)d_out;

  // ws layout (~43 MB):
  //  [0,8)    Qhi  (aliased as AOhi after attn)
  //  [8,16)   VThi
  //  [16,24)  xhi  -+ dead after gemm_qkv; [16,32) reused for Oo (bf16, 14.7MB)
  //  [24,32)  xlo  -+
  //  [32,34)  Wqhi  [34,36) Wqlo  [36,38) Wkb  [38,40) Wvb  [40,42) Wob
  //  [42,..)  norms (256 KB), sel (57 KB), Ol (458 KB)
  // Khi lives in d_out (8 of 16 MB) — dead until gemm_out rewrites d_out.
  const size_t MB = 1u << 20;
  char* ws = (char*)d_ws;
  bf16_t* Qhi  = (bf16_t*)(ws);
  bf16_t* VThi = (bf16_t*)(ws + 8 * MB);
  bf16_t* xhi  = (bf16_t*)(ws + 16 * MB);
  bf16_t* xlo  = (bf16_t*)(ws + 24 * MB);
  bf16_t* Oo   = (bf16_t*)(ws + 16 * MB);         // aliases xhi/xlo
  bf16_t* Wqhi = (bf16_t*)(ws + 32 * MB);
  bf16_t* Wqlo = (bf16_t*)(ws + 34 * MB);
  bf16_t* Wkb  = (bf16_t*)(ws + 36 * MB);
  bf16_t* Wvb  = (bf16_t*)(ws + 38 * MB);
  bf16_t* Wob  = (bf16_t*)(ws + 40 * MB);
  float*  norms = (float*)(ws + 42 * MB);
  int*    sel   = (int*)(ws + 42 * MB + (256u << 10));
  float*  Ol    = (float*)(ws + 42 * MB + (320u << 10));
  bf16_t* AOhi = Qhi;
  bf16_t* Khi = (bf16_t*)d_out;

  dim3 blk(256);
  prep_kernel<<<dim3(8192), blk, 0, stream>>>(x, Wq, Wk, Wv, Wo,
                                              xhi, xlo, Wqhi, Wqlo, Wkb, Wvb, Wob);
  gemm_qkv<<<dim3(8, 32, 3), blk, 0, stream>>>(xhi, xlo, Wqhi, Wqlo, Wkb, Wvb,
                                               bq, bk, bv, Qhi, Khi, VThi, norms);
  topk_kernel<<<dim3(32), dim3(1024), 0, stream>>>(norms, sel);
  attn_kernel<<<dim3(32 * 7 * KSPLIT), blk, 0, stream>>>(Qhi, Khi, VThi, sel, Ol, Oo);
  meanfill_kernel<<<dim3(32, 8), blk, 0, stream>>>(VThi, AOhi);
  combine_kernel<<<dim3(32, 28), blk, 0, stream>>>(Ol, Oo, sel, AOhi);
  gemm_out<<<dim3(8, 64), blk, 0, stream>>>(AOhi, Wob, bo, out);
}